// Round 1
// baseline (1876.774 us; speedup 1.0000x reference)
//
#include <hip/hip_runtime.h>
#include <hip/hip_bf16.h>

// ---- problem constants ----
#define LF 4095              // encoder output length: (32768-16)/8 + 1
#define NCH 256
#define NLL (NCH * LF)       // per-batch trunk stride (floats)
#define SEQLEN 32768
#define NBATCH 4

// ---------------------------------------------------------------------------
// Input conversion: runtime dtype probe.
// me_ln_g (d_in[4]) is all 1.0. First 4 bytes:
//   f32  -> 0x3F800000
//   bf16 -> 0x3F80 0x3F80 -> u32 0x3F803F80
// ---------------------------------------------------------------------------
struct CvtArgs { const void* src[21]; long long off[21]; int n[21]; };

__global__ __launch_bounds__(256) void k_convert(CvtArgs a, float* ws, const unsigned* probe) {
    const bool bf = (*probe == 0x3F803F80u);
    const int t = blockIdx.y;
    const int n = a.n[t];
    const float* sf = (const float*)a.src[t];
    const unsigned short* sh = (const unsigned short*)a.src[t];
    float* d = ws + a.off[t];
    for (int i = blockIdx.x * blockDim.x + threadIdx.x; i < n; i += gridDim.x * blockDim.x) {
        float v;
        if (bf) v = __uint_as_float(((unsigned)sh[i]) << 16);
        else    v = sf[i];
        d[i] = v;
    }
}

// ---------------------------------------------------------------------------
// Transpose W[o][c] -> Wt[c][o] so pw inner loop reads 16 contiguous weights
// from a wave-uniform address (-> s_load).
// ---------------------------------------------------------------------------
struct TrEntry { long long soff, doff; int R, C; };
struct TrArgs { TrEntry e[18]; };

__global__ __launch_bounds__(256) void k_transpose(TrArgs a, float* ws) {
    const TrEntry e = a.e[blockIdx.y];
    const int total = e.R * e.C;
    for (int i = blockIdx.x * blockDim.x + threadIdx.x; i < total; i += gridDim.x * blockDim.x) {
        const int r = i / e.C;
        const int c = i - r * e.C;
        ws[e.doff + (long long)c * e.R + r] = ws[e.soff + i];
    }
}

// ---------------------------------------------------------------------------
// Encoder: enc[b,c,l] = sum_t acw[c,t]*ac[b,8l+t] + bcw[c,t]*bc[b,8l+t]
// grid (16, 256, 4), block 256 over l
// ---------------------------------------------------------------------------
__global__ __launch_bounds__(256) void k_encoder(const float* ac, const float* bc,
                                                 const float* acw, const float* bcw, float* enc) {
    __shared__ float wA[16], wB[16];
    const int c = blockIdx.y, b = blockIdx.z;
    if (threadIdx.x < 16)       wA[threadIdx.x] = acw[c * 16 + threadIdx.x];
    else if (threadIdx.x < 32)  wB[threadIdx.x - 16] = bcw[c * 16 + threadIdx.x - 16];
    __syncthreads();
    const int l = blockIdx.x * 256 + threadIdx.x;
    if (l >= LF) return;
    const float* pa = ac + (long long)b * SEQLEN + 8 * l;
    const float* pb = bc + (long long)b * SEQLEN + 8 * l;
    float acc = 0.f;
#pragma unroll
    for (int t = 0; t < 16; t++) acc = fmaf(wA[t], pa[t], fmaf(wB[t], pb[t], acc));
    enc[(long long)(b * NCH + c) * LF + l] = acc;
}

// ---------------------------------------------------------------------------
// Channel LayerNorm (optionally fused scalar PReLU before stats).
// Thread per (b,l); loops over 256 channels (coalesced over l).
// ---------------------------------------------------------------------------
__global__ __launch_bounds__(256) void k_ln(const float* in, float* out,
                                            const float* g, const float* beta, const float* act_a) {
    const int idx = blockIdx.x * 256 + threadIdx.x;
    if (idx >= NBATCH * LF) return;
    const int b = idx / LF, l = idx - b * LF;
    const bool pr = (act_a != nullptr);
    const float alpha = pr ? *act_a : 0.f;
    const float* p = in + (long long)b * NLL + l;
    float s = 0.f, ss = 0.f;
    for (int c = 0; c < NCH; c++) {
        float v = p[(long long)c * LF];
        if (pr && v < 0.f) v *= alpha;
        s += v; ss = fmaf(v, v, ss);
    }
    const float mu = s * (1.f / NCH);
    const float var = ss * (1.f / NCH) - mu * mu;
    const float rs = rsqrtf(var + 1e-5f);
    float* q = out + (long long)b * NLL + l;
    for (int c = 0; c < NCH; c++) {
        float v = p[(long long)c * LF];
        if (pr && v < 0.f) v *= alpha;
        q[(long long)c * LF] = (v - mu) * rs * g[c] + beta[c];
    }
}

// ---------------------------------------------------------------------------
// Pointwise GEMM: out[b,o,l] = sum_c W[o,c]*in[b,c,l] + bias[o]
// Wt is transposed (c-major, row length = cout). Wave computes 16 o x 64 l.
// Optional fused residual add, relu, and post-multiply (for the mask step).
// grid (64, cout/64, 4), block 256 (4 waves).
// ---------------------------------------------------------------------------
__global__ __launch_bounds__(256) void k_pw(const float* in, const float* Wt, int cout,
                                            const float* bias, const float* addsrc,
                                            const float* mulsrc, int relu, float* out) {
    const int b = blockIdx.z;
    const int lane = threadIdx.x & 63;
    const int wv = __builtin_amdgcn_readfirstlane(threadIdx.x >> 6);
    const int obase = blockIdx.y * 64 + wv * 16;
    const int l = blockIdx.x * 64 + lane;
    const bool ok = (l < LF);
    const float* ip = in + (long long)b * NLL + l;
    float acc[16];
#pragma unroll
    for (int i = 0; i < 16; i++) acc[i] = bias[obase + i];
    for (int c = 0; c < NCH; c++) {
        const float v = ok ? ip[(long long)c * LF] : 0.f;
        const float* w = Wt + (long long)c * cout + obase;   // wave-uniform -> s_load
#pragma unroll
        for (int i = 0; i < 16; i++) acc[i] = fmaf(w[i], v, acc[i]);
    }
    if (!ok) return;
    const long long ob = (long long)b * cout * LF + (long long)obase * LF + l;
#pragma unroll
    for (int i = 0; i < 16; i++) {
        float r = acc[i];
        if (addsrc) r += addsrc[ob + (long long)i * LF];
        if (relu)   r = fmaxf(r, 0.f);
        if (mulsrc) r *= mulsrc[ob + (long long)i * LF];
        out[ob + (long long)i * LF] = r;
    }
}

// ---------------------------------------------------------------------------
// Involution kernel-gen stage 2: ker[b,k,l] = sum_c w2[k,c]*in[b,c,l] + b2[k]
// in has 64 channels. Thread per (b,l).
// ---------------------------------------------------------------------------
__global__ __launch_bounds__(256) void k_pw2(const float* in, const float* w2, const float* b2, float* ker) {
    const int idx = blockIdx.x * 256 + threadIdx.x;
    if (idx >= NBATCH * LF) return;
    const int b = idx / LF, l = idx - b * LF;
    const float* p = in + (long long)b * 64 * LF + l;
    float a0 = b2[0], a1 = b2[1], a2 = b2[2];
#pragma unroll 4
    for (int c = 0; c < 64; c++) {
        const float v = p[(long long)c * LF];
        a0 = fmaf(w2[c], v, a0);
        a1 = fmaf(w2[64 + c], v, a1);
        a2 = fmaf(w2[128 + c], v, a2);
    }
    float* q = ker + (long long)b * 3 * LF + l;
    q[0] = a0; q[LF] = a1; q[2 * LF] = a2;
}

// ---------------------------------------------------------------------------
// Involution apply + per-channel PReLU:
// out[b,c,l] = prelu( sum_k ker[b,k,l]*m[b,c,l+k-1], pa[c] )
// grid (16, 256, 4), block 256 over l.
// ---------------------------------------------------------------------------
__global__ __launch_bounds__(256) void k_inv_apply(const float* m, const float* ker,
                                                   const float* pa, float* out) {
    const int l = blockIdx.x * 256 + threadIdx.x;
    if (l >= LF) return;
    const int c = blockIdx.y, b = blockIdx.z;
    const float* kp = ker + (long long)b * 3 * LF;
    const float k0 = kp[l], k1 = kp[LF + l], k2 = kp[2 * LF + l];
    const float* mp = m + (long long)(b * NCH + c) * LF;
    const float x0 = (l > 0) ? mp[l - 1] : 0.f;
    const float x1 = mp[l];
    const float x2 = (l < LF - 1) ? mp[l + 1] : 0.f;
    float r = k0 * x0 + k1 * x1 + k2 * x2;
    const float a = pa[c];
    out[(long long)(b * NCH + c) * LF + l] = (r >= 0.f) ? r : a * r;
}

// ---------------------------------------------------------------------------
// Transposed conv (stride 8, L 16): out[b,t] = sum_c x[b,c,t>>3]*w[c,t&7]
//                                            + sum_c x[b,c,(t>>3)-1]*w[c,(t&7)+8]
// Stores bf16 or f32 per the dtype probe.
// ---------------------------------------------------------------------------
__global__ __launch_bounds__(256) void k_deconv(const float* masked, const float* dw,
                                                void* dout, const unsigned* probe) {
    const int t = blockIdx.x * 256 + threadIdx.x;  // 0..32767
    const int b = blockIdx.y;
    const int j0 = t & 7, l0 = t >> 3;
    const float* mp = masked + (long long)b * NLL;
    float acc = 0.f;
    if (l0 < LF) {
        for (int c = 0; c < NCH; c++) acc = fmaf(mp[(long long)c * LF + l0], dw[c * 16 + j0], acc);
    }
    if (l0 >= 1) {
        for (int c = 0; c < NCH; c++) acc = fmaf(mp[(long long)c * LF + l0 - 1], dw[c * 16 + j0 + 8], acc);
    }
    if (*probe == 0x3F803F80u) ((__hip_bfloat16*)dout)[(long long)b * SEQLEN + t] = __float2bfloat16(acc);
    else                       ((float*)dout)[(long long)b * SEQLEN + t] = acc;
}

// ---------------------------------------------------------------------------
// Host launch
// ---------------------------------------------------------------------------
extern "C" void kernel_launch(void* const* d_in, const int* in_sizes, int n_in,
                              void* d_out, int out_size, void* d_ws, size_t ws_size,
                              hipStream_t stream) {
    float* W = (float*)d_ws;
    const unsigned* probe = (const unsigned*)d_in[4];  // me_ln_g (all ones)

    // element offsets of converted-f32 inputs inside ws (setup_inputs order)
    static const long long O[21] = {
        0,        // 0  noisy_ac  131072
        131072,   // 1  noisy_bc  131072
        262144,   // 2  ac_w        4096
        266240,   // 3  bc_w        4096
        270336,   // 4  me_ln_g      256
        270592,   // 5  me_ln_b      256
        270848,   // 6  me_init_w  65536
        336384,   // 7  me_init_b    256
        336640,   // 8  blk_ln_g    1024
        337664,   // 9  blk_ln_b    1024
        338688,   // 10 blk_act_a      4
        338692,   // 11 inv_w1    196608
        535300,   // 12 inv_b1       768
        536068,   // 13 inv_w2      2304
        538372,   // 14 inv_b2        36
        538408,   // 15 inv_prelu_a 3072
        541480,   // 16 skip_w    262144
        803624,   // 17 skip_b      1024
        804648,   // 18 me_final_w 65536
        870184,   // 19 me_final_b   256
        870440    // 20 dec_w       4096
    };
    const long long TB          = 874560;            // transposed weights base
    const long long ME_INIT_WT  = TB;
    const long long ME_FINAL_WT = TB + 65536;
    const long long SKIP_WT     = TB + 131072;       // 4 x 65536
    const long long INV_W1T     = TB + 393216;       // 12 x 16384
    const long long ENC  = 1464384;                  // each big buffer: 4*256*4095 floats
    const long long T1   = ENC + 4193280;
    const long long T2   = T1 + 4193280;
    const long long T3   = T2 + 4193280;
    const long long T4   = T3 + 4193280;
    const long long INV1 = T4 + 4193280;             // 4*64*4095
    const long long KER  = INV1 + 1048320;           // 4*3*4095
    // total ws use: ~94.1 MB (floats)

    CvtArgs ca;
    for (int i = 0; i < 21; i++) { ca.src[i] = d_in[i]; ca.off[i] = O[i]; ca.n[i] = in_sizes[i]; }
    k_convert<<<dim3(256, 21, 1), 256, 0, stream>>>(ca, W, probe);

    TrArgs ta;
    int e = 0;
    ta.e[e++] = {O[6],  ME_INIT_WT,  256, 256};
    ta.e[e++] = {O[18], ME_FINAL_WT, 256, 256};
    for (int b = 0; b < 4; b++)   ta.e[e++] = {O[16] + (long long)b * 65536, SKIP_WT + (long long)b * 65536, 256, 256};
    for (int bp = 0; bp < 12; bp++) ta.e[e++] = {O[11] + (long long)bp * 16384, INV_W1T + (long long)bp * 16384, 64, 256};
    k_transpose<<<dim3(64, 18, 1), 256, 0, stream>>>(ta, W);

    k_encoder<<<dim3(16, 256, 4), 256, 0, stream>>>(W + O[0], W + O[1], W + O[2], W + O[3], W + ENC);

    // me LN (no prelu)
    k_ln<<<64, 256, 0, stream>>>(W + ENC, W + T1, W + O[4], W + O[5], nullptr);

    // me init pw: T1 -> T2 (trunk)
    k_pw<<<dim3(64, 4, 4), 256, 0, stream>>>(W + T1, W + ME_INIT_WT, 256, W + O[7],
                                             nullptr, nullptr, 0, W + T2);

    for (int b = 0; b < 4; b++) {
        // prelu(scalar) + LN: T2 -> T1 (= xn)
        k_ln<<<64, 256, 0, stream>>>(W + T2, W + T1, W + O[8] + b * 256, W + O[9] + b * 256, W + O[10] + b);

        long long src = T1;
        const long long dsts[3] = {T3, T4, T3};
        for (int p = 0; p < 3; p++) {
            const int bp = b * 3 + p;
            k_pw<<<dim3(64, 1, 4), 256, 0, stream>>>(W + src, W + INV_W1T + (long long)bp * 16384, 64,
                                                     W + O[12] + bp * 64, nullptr, nullptr, 0, W + INV1);
            k_pw2<<<64, 256, 0, stream>>>(W + INV1, W + O[13] + bp * 192, W + O[14] + bp * 3, W + KER);
            k_inv_apply<<<dim3(16, 256, 4), 256, 0, stream>>>(W + src, W + KER, W + O[15] + bp * 256, W + dsts[p]);
            src = dsts[p];
        }
        // x = m(T3) + skip_pw(xn=T1) -> T2
        k_pw<<<dim3(64, 4, 4), 256, 0, stream>>>(W + T1, W + SKIP_WT + (long long)b * 65536, 256,
                                                 W + O[17] + b * 256, W + T3, nullptr, 0, W + T2);
    }

    // masked = enc * relu(me_final_pw(T2)) -> T1
    k_pw<<<dim3(64, 4, 4), 256, 0, stream>>>(W + T2, W + ME_FINAL_WT, 256, W + O[19],
                                             nullptr, W + ENC, 1, W + T1);

    // deconv -> d_out (dtype per probe)
    k_deconv<<<dim3(128, 4), 256, 0, stream>>>(W + T1, W + O[20], d_out, probe);
}

// Round 2
// 668.948 us; speedup vs baseline: 2.8056x; 2.8056x over previous
//
#include <hip/hip_runtime.h>
#include <hip/hip_bf16.h>

// ---- problem constants ----
#define LF 4095              // encoder output length: (32768-16)/8 + 1
#define SEQLEN 32768
#define NBATCH 4
#define MTOT (NBATCH * LF)   // 16380 trunk rows, layout [m][256] channels-last

// ---------------------------------------------------------------------------
// Input conversion with runtime dtype probe (me_ln_g is all 1.0):
//   f32 -> 0x3F800000 ; bf16 -> 0x3F803F80
// ---------------------------------------------------------------------------
struct CvtArgs { const void* src[21]; long long off[21]; int n[21]; };

__global__ __launch_bounds__(256) void k_convert(CvtArgs a, float* ws, const unsigned* probe) {
    const bool bf = (*probe == 0x3F803F80u);
    const int t = blockIdx.y;
    const int n = a.n[t];
    const float* sf = (const float*)a.src[t];
    const unsigned short* sh = (const unsigned short*)a.src[t];
    float* d = ws + a.off[t];
    for (int i = blockIdx.x * blockDim.x + threadIdx.x; i < n; i += gridDim.x * blockDim.x) {
        d[i] = bf ? __uint_as_float(((unsigned)sh[i]) << 16) : sf[i];
    }
}

// ---------------------------------------------------------------------------
// Small transposes: src [R][C] -> dst [C][R]  (conv weights to tap-major)
// ---------------------------------------------------------------------------
struct TrEntry { long long soff, doff; int R, C; };
struct TrArgs { TrEntry e[3]; };

__global__ __launch_bounds__(256) void k_transpose(TrArgs a, float* ws) {
    const TrEntry e = a.e[blockIdx.y];
    const int total = e.R * e.C;
    for (int i = blockIdx.x * blockDim.x + threadIdx.x; i < total; i += gridDim.x * blockDim.x) {
        const int r = i / e.C;
        const int c = i - r * e.C;
        ws[e.doff + (long long)c * e.R + r] = ws[e.soff + i];
    }
}

// ---------------------------------------------------------------------------
// Encoder -> channels-last enc[m][c]. Block: 256 threads = c; 8 l's per block.
// Weights pre-transposed to [t][256] so per-thread loads coalesce over c.
// ---------------------------------------------------------------------------
__global__ __launch_bounds__(256) void k_encoder(const float* __restrict__ ac, const float* __restrict__ bc,
                                                 const float* __restrict__ wTa, const float* __restrict__ wTb,
                                                 float* __restrict__ enc) {
    const int c = threadIdx.x;
    const int b = blockIdx.y;
    const int l0 = blockIdx.x * 8;
    float wa[16], wb[16];
#pragma unroll
    for (int t = 0; t < 16; t++) { wa[t] = wTa[t * 256 + c]; wb[t] = wTb[t * 256 + c]; }
    for (int dl = 0; dl < 8; dl++) {
        const int l = l0 + dl;
        if (l >= LF) break;
        const float* pa = ac + (long long)b * SEQLEN + 8 * l;
        const float* pb = bc + (long long)b * SEQLEN + 8 * l;
        float acc = 0.f;
#pragma unroll
        for (int t = 0; t < 16; t++) acc = fmaf(wa[t], pa[t], fmaf(wb[t], pb[t], acc));
        enc[((long long)b * LF + l) * 256 + c] = acc;
    }
}

// ---------------------------------------------------------------------------
// Channel LayerNorm over 256 contiguous channels, one wave per row.
// Optional fused scalar PReLU before stats. grid 4095 x 4 waves = 16380 rows.
// ---------------------------------------------------------------------------
__global__ __launch_bounds__(256) void k_ln(const float* __restrict__ in, float* __restrict__ out,
                                            const float* __restrict__ g, const float* __restrict__ be,
                                            const float* __restrict__ act_a) {
    const int wave = threadIdx.x >> 6, lane = threadIdx.x & 63;
    const long long row = (long long)blockIdx.x * 4 + wave;   // grid 4095 -> rows < 16380
    float4 v = *(const float4*)(in + row * 256 + lane * 4);
    if (act_a) {
        const float al = *act_a;
        v.x = v.x < 0.f ? al * v.x : v.x;  v.y = v.y < 0.f ? al * v.y : v.y;
        v.z = v.z < 0.f ? al * v.z : v.z;  v.w = v.w < 0.f ? al * v.w : v.w;
    }
    float s  = v.x + v.y + v.z + v.w;
    float ss = fmaf(v.x, v.x, fmaf(v.y, v.y, fmaf(v.z, v.z, v.w * v.w)));
#pragma unroll
    for (int off = 32; off; off >>= 1) { s += __shfl_xor(s, off, 64); ss += __shfl_xor(ss, off, 64); }
    const float mu = s * (1.f / 256.f);
    const float var = ss * (1.f / 256.f) - mu * mu;
    const float rs = rsqrtf(var + 1e-5f);
    const float4 g4 = *(const float4*)(g + lane * 4);
    const float4 b4 = *(const float4*)(be + lane * 4);
    float4 o;
    o.x = fmaf((v.x - mu) * rs, g4.x, b4.x);
    o.y = fmaf((v.y - mu) * rs, g4.y, b4.y);
    o.z = fmaf((v.z - mu) * rs, g4.z, b4.z);
    o.w = fmaf((v.w - mu) * rs, g4.w, b4.w);
    *(float4*)(out + row * 256 + lane * 4) = o;
}

// ---------------------------------------------------------------------------
// Tiled f32 GEMM: out[m][o] = sum_c A[m][c]*Bw[o][c] + bias[o]  (K=256)
// Block 256 thr, C-tile 64x64, 4x4 microtile, K-chunk 16. LDS tiles stored
// transposed [k][m] (2-way conflicts only = free). Epilogue via LDS for
// coalesced stores; fused addsrc / relu / mulsrc.
// grid (256, cout/64)
// ---------------------------------------------------------------------------
__global__ __launch_bounds__(256) void k_gemm(const float* __restrict__ A, const float* __restrict__ Bw,
                                              const float* __restrict__ bias,
                                              const float* __restrict__ addsrc,
                                              const float* __restrict__ mulsrc, int relu,
                                              float* __restrict__ out, int cout) {
    __shared__ float As[16][68];
    __shared__ float Bs[16][68];
    __shared__ float Cs[64][68];
    const int t = threadIdx.x;
    const int m0 = blockIdx.x * 64;
    const int o0 = blockIdx.y * 64;
    const int tm = t & 15, to = t >> 4;        // 16 x 16 threads, each 4m x 4o
    const int lr = t >> 2;                     // load row 0..63
    const int lc = (t & 3) * 4;                // load col (float4) 0..12
    float acc[4][4] = {};
    int am = m0 + lr; if (am >= MTOT) am = MTOT - 1;   // clamp, writes guarded
    const float* ap = A + (long long)am * 256 + lc;
    const float* bp = Bw + (long long)(o0 + lr) * 256 + lc;
    for (int k0 = 0; k0 < 256; k0 += 16) {
        const float4 a4 = *(const float4*)(ap + k0);
        const float4 b4 = *(const float4*)(bp + k0);
        __syncthreads();
        As[lc + 0][lr] = a4.x; As[lc + 1][lr] = a4.y; As[lc + 2][lr] = a4.z; As[lc + 3][lr] = a4.w;
        Bs[lc + 0][lr] = b4.x; Bs[lc + 1][lr] = b4.y; Bs[lc + 2][lr] = b4.z; Bs[lc + 3][lr] = b4.w;
        __syncthreads();
#pragma unroll
        for (int k = 0; k < 16; k++) {
            const float4 av = *(const float4*)&As[k][tm * 4];
            const float4 bv = *(const float4*)&Bs[k][to * 4];
            const float a[4] = {av.x, av.y, av.z, av.w};
            const float b[4] = {bv.x, bv.y, bv.z, bv.w};
#pragma unroll
            for (int i = 0; i < 4; i++)
#pragma unroll
                for (int j = 0; j < 4; j++) acc[i][j] = fmaf(a[i], b[j], acc[i][j]);
        }
    }
    __syncthreads();
#pragma unroll
    for (int i = 0; i < 4; i++)
#pragma unroll
        for (int j = 0; j < 4; j++) Cs[tm * 4 + i][to * 4 + j] = acc[i][j];
    __syncthreads();
    const int row = t >> 2;
    const int m = m0 + row;
    if (m >= MTOT) return;
    const long long ob = (long long)m * cout + o0;
#pragma unroll
    for (int rep = 0; rep < 4; rep++) {
        const int c = (t & 3) * 4 + rep * 16;
        const float4 bi = *(const float4*)(bias + o0 + c);
        float4 r;
        r.x = Cs[row][c + 0] + bi.x; r.y = Cs[row][c + 1] + bi.y;
        r.z = Cs[row][c + 2] + bi.z; r.w = Cs[row][c + 3] + bi.w;
        if (addsrc) {
            const float4 ad = *(const float4*)(addsrc + ob + c);
            r.x += ad.x; r.y += ad.y; r.z += ad.z; r.w += ad.w;
        }
        if (relu) { r.x = fmaxf(r.x, 0.f); r.y = fmaxf(r.y, 0.f); r.z = fmaxf(r.z, 0.f); r.w = fmaxf(r.w, 0.f); }
        if (mulsrc) {
            const float4 mu = *(const float4*)(mulsrc + ob + c);
            r.x *= mu.x; r.y *= mu.y; r.z *= mu.z; r.w *= mu.w;
        }
        *(float4*)(out + ob + c) = r;
    }
}

// ---------------------------------------------------------------------------
// Involution kernel-gen, fully fused: inv1 = A·w1^T + b1 (cout=64) kept in
// LDS; ker[m][k] = sum_o w2[k][o]*inv1[m][o] + b2[k] computed in-epilogue.
// grid 256 blocks (64 rows each).
// ---------------------------------------------------------------------------
__global__ __launch_bounds__(256) void k_pw_ker(const float* __restrict__ A, const float* __restrict__ W1,
                                                const float* __restrict__ b1, const float* __restrict__ w2,
                                                const float* __restrict__ b2, float* __restrict__ ker) {
    __shared__ float As[16][68];
    __shared__ float Bs[16][68];
    __shared__ float Cs[64][69];   // stride 69: ker-phase column walk conflict-free
    const int t = threadIdx.x;
    const int m0 = blockIdx.x * 64;
    const int tm = t & 15, to = t >> 4;
    const int lr = t >> 2;
    const int lc = (t & 3) * 4;
    float acc[4][4] = {};
    int am = m0 + lr; if (am >= MTOT) am = MTOT - 1;
    const float* ap = A + (long long)am * 256 + lc;
    const float* bp = W1 + (long long)lr * 256 + lc;   // cout = 64 rows, all valid
    for (int k0 = 0; k0 < 256; k0 += 16) {
        const float4 a4 = *(const float4*)(ap + k0);
        const float4 b4 = *(const float4*)(bp + k0);
        __syncthreads();
        As[lc + 0][lr] = a4.x; As[lc + 1][lr] = a4.y; As[lc + 2][lr] = a4.z; As[lc + 3][lr] = a4.w;
        Bs[lc + 0][lr] = b4.x; Bs[lc + 1][lr] = b4.y; Bs[lc + 2][lr] = b4.z; Bs[lc + 3][lr] = b4.w;
        __syncthreads();
#pragma unroll
        for (int k = 0; k < 16; k++) {
            const float4 av = *(const float4*)&As[k][tm * 4];
            const float4 bv = *(const float4*)&Bs[k][to * 4];
            const float a[4] = {av.x, av.y, av.z, av.w};
            const float b[4] = {bv.x, bv.y, bv.z, bv.w};
#pragma unroll
            for (int i = 0; i < 4; i++)
#pragma unroll
                for (int j = 0; j < 4; j++) acc[i][j] = fmaf(a[i], b[j], acc[i][j]);
        }
    }
    __syncthreads();
#pragma unroll
    for (int i = 0; i < 4; i++)
#pragma unroll
        for (int j = 0; j < 4; j++) Cs[tm * 4 + i][to * 4 + j] = acc[i][j] + b1[to * 4 + j];
    __syncthreads();
    if (t < 192) {
        const int m = t & 63, k = t >> 6;
        if (m0 + m < MTOT) {
            float s = b2[k];
            const float* wr = w2 + k * 64;
#pragma unroll 8
            for (int o = 0; o < 64; o++) s = fmaf(wr[o], Cs[m][o], s);
            ker[(long long)(m0 + m) * 3 + k] = s;
        }
    }
}

// ---------------------------------------------------------------------------
// Involution apply + per-channel PReLU. Wave per row, float4 over channels.
// out[m][c] = prelu(k0*src[m-1][c] + k1*src[m][c] + k2*src[m+1][c], pa[c])
// with zero-pad at batch-internal l boundaries. grid (1024, 4).
// ---------------------------------------------------------------------------
__global__ __launch_bounds__(256) void k_apply(const float* __restrict__ src, const float* __restrict__ ker,
                                               const float* __restrict__ pa, float* __restrict__ out) {
    const int wave = threadIdx.x >> 6, lane = threadIdx.x & 63;
    const int l = blockIdx.x * 4 + wave;
    if (l >= LF) return;
    const int b = blockIdx.y;
    const long long row = (long long)b * LF + l;
    const float k0 = ker[row * 3 + 0], k1 = ker[row * 3 + 1], k2 = ker[row * 3 + 2];
    const float4 x1 = *(const float4*)(src + row * 256 + lane * 4);
    float4 x0 = {0.f, 0.f, 0.f, 0.f}, x2 = {0.f, 0.f, 0.f, 0.f};
    if (l > 0)      x0 = *(const float4*)(src + (row - 1) * 256 + lane * 4);
    if (l < LF - 1) x2 = *(const float4*)(src + (row + 1) * 256 + lane * 4);
    float4 r;
    r.x = fmaf(k0, x0.x, fmaf(k1, x1.x, k2 * x2.x));
    r.y = fmaf(k0, x0.y, fmaf(k1, x1.y, k2 * x2.y));
    r.z = fmaf(k0, x0.z, fmaf(k1, x1.z, k2 * x2.z));
    r.w = fmaf(k0, x0.w, fmaf(k1, x1.w, k2 * x2.w));
    const float4 a4 = *(const float4*)(pa + lane * 4);
    r.x = r.x >= 0.f ? r.x : a4.x * r.x;
    r.y = r.y >= 0.f ? r.y : a4.y * r.y;
    r.z = r.z >= 0.f ? r.z : a4.z * r.z;
    r.w = r.w >= 0.f ? r.w : a4.w * r.w;
    *(float4*)(out + row * 256 + lane * 4) = r;
}

// ---------------------------------------------------------------------------
// Transposed conv: out[b,t] = row(t>>3)·dwT[t&7] + row((t>>3)-1)·dwT[(t&7)+8]
// Wave per output sample; float4 + shuffle reduce. Stores bf16/f32 per probe.
// grid (8192, 4).
// ---------------------------------------------------------------------------
__global__ __launch_bounds__(256) void k_deconv(const float* __restrict__ masked, const float* __restrict__ dwT,
                                                void* dout, const unsigned* probe) {
    const int wave = threadIdx.x >> 6, lane = threadIdx.x & 63;
    const int tt = blockIdx.x * 4 + wave;    // 0..32767
    const int b = blockIdx.y;
    const int j0 = tt & 7, l0 = tt >> 3;
    float4 acc = {0.f, 0.f, 0.f, 0.f};
    if (l0 < LF) {
        const float4 x = *(const float4*)(masked + ((long long)b * LF + l0) * 256 + lane * 4);
        const float4 w = *(const float4*)(dwT + j0 * 256 + lane * 4);
        acc.x = fmaf(x.x, w.x, acc.x); acc.y = fmaf(x.y, w.y, acc.y);
        acc.z = fmaf(x.z, w.z, acc.z); acc.w = fmaf(x.w, w.w, acc.w);
    }
    if (l0 >= 1) {
        const float4 x = *(const float4*)(masked + ((long long)b * LF + l0 - 1) * 256 + lane * 4);
        const float4 w = *(const float4*)(dwT + (j0 + 8) * 256 + lane * 4);
        acc.x = fmaf(x.x, w.x, acc.x); acc.y = fmaf(x.y, w.y, acc.y);
        acc.z = fmaf(x.z, w.z, acc.z); acc.w = fmaf(x.w, w.w, acc.w);
    }
    float s = acc.x + acc.y + acc.z + acc.w;
#pragma unroll
    for (int off = 32; off; off >>= 1) s += __shfl_xor(s, off, 64);
    if (lane == 0) {
        if (*probe == 0x3F803F80u) ((__hip_bfloat16*)dout)[(long long)b * SEQLEN + tt] = __float2bfloat16(s);
        else                       ((float*)dout)[(long long)b * SEQLEN + tt] = s;
    }
}

// ---------------------------------------------------------------------------
// Host launch
// ---------------------------------------------------------------------------
extern "C" void kernel_launch(void* const* d_in, const int* in_sizes, int n_in,
                              void* d_out, int out_size, void* d_ws, size_t ws_size,
                              hipStream_t stream) {
    float* W = (float*)d_ws;
    const unsigned* probe = (const unsigned*)d_in[4];  // me_ln_g (all ones)

    static const long long O[21] = {
        0, 131072, 262144, 266240, 270336, 270592, 270848, 336384, 336640, 337664,
        338688, 338692, 535300, 536068, 538372, 538408, 541480, 803624, 804648,
        870184, 870440
    };
    const long long ACWT = 874560, BCWT = 878656, DWT = 882752;
    const long long ENC = 886848;                 // big bufs: 16384*256 floats each
    const long long T1 = ENC + 4194304;
    const long long T2 = T1 + 4194304;
    const long long T3 = T2 + 4194304;
    const long long T4 = T3 + 4194304;
    const long long KER = T4 + 4194304;           // 16380*3; end ~87.6 MB

    CvtArgs ca;
    for (int i = 0; i < 21; i++) { ca.src[i] = d_in[i]; ca.off[i] = O[i]; ca.n[i] = in_sizes[i]; }
    k_convert<<<dim3(256, 21), 256, 0, stream>>>(ca, W, probe);

    TrArgs ta;
    ta.e[0] = {O[2],  ACWT, 256, 16};
    ta.e[1] = {O[3],  BCWT, 256, 16};
    ta.e[2] = {O[20], DWT,  256, 16};
    k_transpose<<<dim3(16, 3), 256, 0, stream>>>(ta, W);

    k_encoder<<<dim3(512, 4), 256, 0, stream>>>(W + O[0], W + O[1], W + ACWT, W + BCWT, W + ENC);

    k_ln<<<LF, 256, 0, stream>>>(W + ENC, W + T1, W + O[4], W + O[5], nullptr);

    k_gemm<<<dim3(256, 4), 256, 0, stream>>>(W + T1, W + O[6], W + O[7],
                                             nullptr, nullptr, 0, W + T2, 256);

    for (int b = 0; b < 4; b++) {
        k_ln<<<LF, 256, 0, stream>>>(W + T2, W + T1, W + O[8] + b * 256, W + O[9] + b * 256, W + O[10] + b);

        long long src = T1;
        const long long dsts[3] = {T3, T4, T3};
        for (int p = 0; p < 3; p++) {
            const int bp = b * 3 + p;
            k_pw_ker<<<256, 256, 0, stream>>>(W + src, W + O[11] + (long long)bp * 16384,
                                              W + O[12] + bp * 64, W + O[13] + bp * 192,
                                              W + O[14] + bp * 3, W + KER);
            k_apply<<<dim3(1024, 4), 256, 0, stream>>>(W + src, W + KER, W + O[15] + bp * 256, W + dsts[p]);
            src = dsts[p];
        }
        k_gemm<<<dim3(256, 4), 256, 0, stream>>>(W + T1, W + O[16] + (long long)b * 65536,
                                                 W + O[17] + b * 256, W + T3, nullptr, 0, W + T2, 256);
    }

    k_gemm<<<dim3(256, 4), 256, 0, stream>>>(W + T2, W + O[18], W + O[19],
                                             nullptr, W + ENC, 1, W + T3, 256);

    k_deconv<<<dim3(8192, 4), 256, 0, stream>>>(W + T3, W + DWT, d_out, probe);
}

// Round 3
// 455.803 us; speedup vs baseline: 4.1175x; 1.4676x over previous
//
#include <hip/hip_runtime.h>
#include <hip/hip_bf16.h>

// ---- problem constants ----
#define LF 4095              // encoder output length: (32768-16)/8 + 1
#define SEQLEN 32768
#define NBATCH 4
#define MTOT (NBATCH * LF)   // 16380 trunk rows, layout [m][256] channels-last

typedef __attribute__((ext_vector_type(8))) short short8;   // 8 bf16 (4 VGPRs)
typedef __attribute__((ext_vector_type(4))) float f32x4;

__device__ __forceinline__ float bf2f(unsigned short u) {
    return __uint_as_float(((unsigned)u) << 16);
}
__device__ __forceinline__ unsigned short f2bf(float f) {   // round-nearest-even
    unsigned u = __float_as_uint(f);
    return (unsigned short)((u + 0x7FFFu + ((u >> 16) & 1u)) >> 16);
}

// ---------------------------------------------------------------------------
// Input conversion with runtime dtype probe (me_ln_g is all 1.0):
//   f32 -> 0x3F800000 ; bf16 -> 0x3F803F80
// ---------------------------------------------------------------------------
struct CvtArgs { const void* src[21]; long long off[21]; int n[21]; };

__global__ __launch_bounds__(256) void k_convert(CvtArgs a, float* ws, const unsigned* probe) {
    const bool bf = (*probe == 0x3F803F80u);
    const int t = blockIdx.y;
    const int n = a.n[t];
    const float* sf = (const float*)a.src[t];
    const unsigned short* sh = (const unsigned short*)a.src[t];
    float* d = ws + a.off[t];
    for (int i = blockIdx.x * blockDim.x + threadIdx.x; i < n; i += gridDim.x * blockDim.x) {
        d[i] = bf ? bf2f(sh[i]) : sf[i];
    }
}

// f32 staged weights -> bf16 arena
struct CastArgs { long long soff[4], doff[4]; int n[4]; };

__global__ __launch_bounds__(256) void k_cast(CastArgs a, const float* Wf, unsigned short* H) {
    const int e = blockIdx.y;
    const int n = a.n[e];
    const float* s = Wf + a.soff[e];
    unsigned short* d = H + a.doff[e];
    for (int i = blockIdx.x * blockDim.x + threadIdx.x; i < n; i += gridDim.x * blockDim.x)
        d[i] = f2bf(s[i]);
}

// ---------------------------------------------------------------------------
// Small transposes: src [R][C] -> dst [C][R]  (conv weights to tap-major)
// ---------------------------------------------------------------------------
struct TrEntry { long long soff, doff; int R, C; };
struct TrArgs { TrEntry e[3]; };

__global__ __launch_bounds__(256) void k_transpose(TrArgs a, float* ws) {
    const TrEntry e = a.e[blockIdx.y];
    const int total = e.R * e.C;
    for (int i = blockIdx.x * blockDim.x + threadIdx.x; i < total; i += gridDim.x * blockDim.x) {
        const int r = i / e.C;
        const int c = i - r * e.C;
        ws[e.doff + (long long)c * e.R + r] = ws[e.soff + i];
    }
}

// ---------------------------------------------------------------------------
// Encoder -> channels-last enc[m][c] (f32). Block: 256 threads = c.
// ---------------------------------------------------------------------------
__global__ __launch_bounds__(256) void k_encoder(const float* __restrict__ ac, const float* __restrict__ bc,
                                                 const float* __restrict__ wTa, const float* __restrict__ wTb,
                                                 float* __restrict__ enc) {
    const int c = threadIdx.x;
    const int b = blockIdx.y;
    const int l0 = blockIdx.x * 8;
    float wa[16], wb[16];
#pragma unroll
    for (int t = 0; t < 16; t++) { wa[t] = wTa[t * 256 + c]; wb[t] = wTb[t * 256 + c]; }
    for (int dl = 0; dl < 8; dl++) {
        const int l = l0 + dl;
        if (l >= LF) break;
        const float* pa = ac + (long long)b * SEQLEN + 8 * l;
        const float* pb = bc + (long long)b * SEQLEN + 8 * l;
        float acc = 0.f;
#pragma unroll
        for (int t = 0; t < 16; t++) acc = fmaf(wa[t], pa[t], fmaf(wb[t], pb[t], acc));
        enc[((long long)b * LF + l) * 256 + c] = acc;
    }
}

// ---------------------------------------------------------------------------
// Channel LayerNorm, one wave per row; optional fused scalar PReLU.
// Input f32 (in_f32=1) or bf16; output bf16. grid 4095 (x4 waves = 16380 rows)
// ---------------------------------------------------------------------------
__global__ __launch_bounds__(256) void k_ln(const void* __restrict__ in, int in_f32,
                                            unsigned short* __restrict__ out,
                                            const float* __restrict__ g, const float* __restrict__ be,
                                            const float* __restrict__ act_a) {
    const int wave = threadIdx.x >> 6, lane = threadIdx.x & 63;
    const long long row = (long long)blockIdx.x * 4 + wave;
    float v[4];
    if (in_f32) {
        const float4 f = *(const float4*)((const float*)in + row * 256 + lane * 4);
        v[0] = f.x; v[1] = f.y; v[2] = f.z; v[3] = f.w;
    } else {
        const ushort4 u = *(const ushort4*)((const unsigned short*)in + row * 256 + lane * 4);
        v[0] = bf2f(u.x); v[1] = bf2f(u.y); v[2] = bf2f(u.z); v[3] = bf2f(u.w);
    }
    if (act_a) {
        const float al = *act_a;
#pragma unroll
        for (int i = 0; i < 4; i++) v[i] = v[i] < 0.f ? al * v[i] : v[i];
    }
    float s = 0.f, ss = 0.f;
#pragma unroll
    for (int i = 0; i < 4; i++) { s += v[i]; ss = fmaf(v[i], v[i], ss); }
#pragma unroll
    for (int off = 32; off; off >>= 1) { s += __shfl_xor(s, off, 64); ss += __shfl_xor(ss, off, 64); }
    const float mu = s * (1.f / 256.f);
    const float var = ss * (1.f / 256.f) - mu * mu;
    const float rs = rsqrtf(var + 1e-5f);
    const float4 g4 = *(const float4*)(g + lane * 4);
    const float4 b4 = *(const float4*)(be + lane * 4);
    ushort4 o;
    o.x = f2bf(fmaf((v[0] - mu) * rs, g4.x, b4.x));
    o.y = f2bf(fmaf((v[1] - mu) * rs, g4.y, b4.y));
    o.z = f2bf(fmaf((v[2] - mu) * rs, g4.z, b4.z));
    o.w = f2bf(fmaf((v[3] - mu) * rs, g4.w, b4.w));
    *(ushort4*)(out + row * 256 + lane * 4) = o;
}

// ---------------------------------------------------------------------------
// bf16 MFMA GEMM: out[m][o] = sum_c A[m][c]*Wt[o][c] + bias[o]   (K=256)
// Block: 256 thr = 4 waves; tile 128(M) x 64(N); each wave 32x64 via 2x4
// frags of mfma_f32_16x16x32_bf16; BK=64 LDS staging (stride 72 bf16).
// Fused: addsrc(bf16) / relu / mulsrc(f32). Output bf16.
// grid (128, cout/64)
// ---------------------------------------------------------------------------
__global__ __launch_bounds__(256) void k_gemm(const unsigned short* __restrict__ A,
                                              const unsigned short* __restrict__ Wt,
                                              const float* __restrict__ bias,
                                              const unsigned short* __restrict__ addsrc,
                                              const float* __restrict__ mulsrc, int relu,
                                              unsigned short* __restrict__ out, int cout) {
    __shared__ unsigned short As[128][72];
    __shared__ unsigned short Bs[64][72];
    const int t = threadIdx.x;
    const int w = t >> 6, lane = t & 63;
    const int quad = lane >> 4, l16 = lane & 15;
    const int m0 = blockIdx.x * 128, o0 = blockIdx.y * 64;
    f32x4 acc[2][4];
#pragma unroll
    for (int i = 0; i < 2; i++)
#pragma unroll
        for (int j = 0; j < 4; j++) acc[i][j] = (f32x4){0.f, 0.f, 0.f, 0.f};

    const int lr = t >> 3;            // 0..31
    const int lc = (t & 7) * 8;       // 0..56 (bf16 col)
    for (int k0 = 0; k0 < 256; k0 += 64) {
        __syncthreads();
#pragma unroll
        for (int it = 0; it < 4; it++) {
            const int r = lr + it * 32;
            long long gm = m0 + r; if (gm >= MTOT) gm = MTOT - 1;
            *(float4*)&As[r][lc] = *(const float4*)&A[gm * 256 + k0 + lc];
        }
#pragma unroll
        for (int it = 0; it < 2; it++) {
            const int r = lr + it * 32;
            *(float4*)&Bs[r][lc] = *(const float4*)&Wt[(long long)(o0 + r) * 256 + k0 + lc];
        }
        __syncthreads();
#pragma unroll
        for (int ks = 0; ks < 64; ks += 32) {
            short8 af[2], bf[4];
#pragma unroll
            for (int i = 0; i < 2; i++) af[i] = *(const short8*)&As[w * 32 + i * 16 + l16][ks + quad * 8];
#pragma unroll
            for (int j = 0; j < 4; j++) bf[j] = *(const short8*)&Bs[j * 16 + l16][ks + quad * 8];
#pragma unroll
            for (int i = 0; i < 2; i++)
#pragma unroll
                for (int j = 0; j < 4; j++)
                    acc[i][j] = __builtin_amdgcn_mfma_f32_16x16x32_bf16(af[i], bf[j], acc[i][j], 0, 0, 0);
        }
    }
    // epilogue: D row = quad*4+reg, col = l16
#pragma unroll
    for (int i = 0; i < 2; i++) {
#pragma unroll
        for (int j = 0; j < 4; j++) {
            const int o = o0 + j * 16 + l16;
            const float bi = bias[o];
#pragma unroll
            for (int r = 0; r < 4; r++) {
                const int m = m0 + w * 32 + i * 16 + quad * 4 + r;
                if (m < MTOT) {
                    const long long idx = (long long)m * cout + o;
                    float v = acc[i][j][r] + bi;
                    if (addsrc) v += bf2f(addsrc[idx]);
                    if (relu)   v = fmaxf(v, 0.f);
                    if (mulsrc) v *= mulsrc[idx];
                    out[idx] = f2bf(v);
                }
            }
        }
    }
}

// ---------------------------------------------------------------------------
// Involution kernel-gen, fused MFMA: C = A(128x256)·W1^T(64x256) + b1 kept in
// LDS; ker[m][k] = sum_o w2[k][o]*C[m][o] + b2[k]. grid 128 blocks.
// ---------------------------------------------------------------------------
__global__ __launch_bounds__(256) void k_pw_ker(const unsigned short* __restrict__ A,
                                                const unsigned short* __restrict__ W1,
                                                const float* __restrict__ b1, const float* __restrict__ w2,
                                                const float* __restrict__ b2, float* __restrict__ ker) {
    __shared__ __align__(16) char smem[33792];
    unsigned short (*As)[72] = (unsigned short(*)[72])smem;               // 18432 B
    unsigned short (*Bs)[72] = (unsigned short(*)[72])(smem + 18432);     //  9216 B
    float (*Cs)[66] = (float(*)[66])smem;                                 // 33792 B (overlays)
    const int t = threadIdx.x;
    const int w = t >> 6, lane = t & 63;
    const int quad = lane >> 4, l16 = lane & 15;
    const int m0 = blockIdx.x * 128;
    f32x4 acc[2][4];
#pragma unroll
    for (int i = 0; i < 2; i++)
#pragma unroll
        for (int j = 0; j < 4; j++) acc[i][j] = (f32x4){0.f, 0.f, 0.f, 0.f};

    const int lr = t >> 3;
    const int lc = (t & 7) * 8;
    for (int k0 = 0; k0 < 256; k0 += 64) {
        __syncthreads();
#pragma unroll
        for (int it = 0; it < 4; it++) {
            const int r = lr + it * 32;
            long long gm = m0 + r; if (gm >= MTOT) gm = MTOT - 1;
            *(float4*)&As[r][lc] = *(const float4*)&A[gm * 256 + k0 + lc];
        }
#pragma unroll
        for (int it = 0; it < 2; it++) {
            const int r = lr + it * 32;
            *(float4*)&Bs[r][lc] = *(const float4*)&W1[(long long)r * 256 + k0 + lc];
        }
        __syncthreads();
#pragma unroll
        for (int ks = 0; ks < 64; ks += 32) {
            short8 af[2], bf[4];
#pragma unroll
            for (int i = 0; i < 2; i++) af[i] = *(const short8*)&As[w * 32 + i * 16 + l16][ks + quad * 8];
#pragma unroll
            for (int j = 0; j < 4; j++) bf[j] = *(const short8*)&Bs[j * 16 + l16][ks + quad * 8];
#pragma unroll
            for (int i = 0; i < 2; i++)
#pragma unroll
                for (int j = 0; j < 4; j++)
                    acc[i][j] = __builtin_amdgcn_mfma_f32_16x16x32_bf16(af[i], bf[j], acc[i][j], 0, 0, 0);
        }
    }
    __syncthreads();   // done reading As/Bs; reuse as Cs
#pragma unroll
    for (int i = 0; i < 2; i++)
#pragma unroll
        for (int j = 0; j < 4; j++) {
            const int o = j * 16 + l16;
            const float bi = b1[o];
#pragma unroll
            for (int r = 0; r < 4; r++)
                Cs[w * 32 + i * 16 + quad * 4 + r][o] = acc[i][j][r] + bi;
        }
    __syncthreads();
    if (t < 128) {
        const int m = m0 + t;
        if (m < MTOT) {
            float s0 = b2[0], s1 = b2[1], s2 = b2[2];
#pragma unroll 8
            for (int o = 0; o < 64; o++) {
                const float c = Cs[t][o];
                s0 = fmaf(w2[o], c, s0);
                s1 = fmaf(w2[64 + o], c, s1);
                s2 = fmaf(w2[128 + o], c, s2);
            }
            float* kp = ker + (long long)m * 3;
            kp[0] = s0; kp[1] = s1; kp[2] = s2;
        }
    }
}

// ---------------------------------------------------------------------------
// Involution apply + per-channel PReLU, bf16 in/out. Wave per row.
// ---------------------------------------------------------------------------
__global__ __launch_bounds__(256) void k_apply(const unsigned short* __restrict__ src,
                                               const float* __restrict__ ker,
                                               const float* __restrict__ pa,
                                               unsigned short* __restrict__ out) {
    const int wave = threadIdx.x >> 6, lane = threadIdx.x & 63;
    const int l = blockIdx.x * 4 + wave;
    if (l >= LF) return;
    const int b = blockIdx.y;
    const long long row = (long long)b * LF + l;
    const float* kp = ker + row * 3;
    const float k0 = kp[0], k1 = kp[1], k2 = kp[2];
    const ushort4 u1 = *(const ushort4*)(src + row * 256 + lane * 4);
    float x1[4] = {bf2f(u1.x), bf2f(u1.y), bf2f(u1.z), bf2f(u1.w)};
    float x0[4] = {0.f, 0.f, 0.f, 0.f}, x2[4] = {0.f, 0.f, 0.f, 0.f};
    if (l > 0) {
        const ushort4 u = *(const ushort4*)(src + (row - 1) * 256 + lane * 4);
        x0[0] = bf2f(u.x); x0[1] = bf2f(u.y); x0[2] = bf2f(u.z); x0[3] = bf2f(u.w);
    }
    if (l < LF - 1) {
        const ushort4 u = *(const ushort4*)(src + (row + 1) * 256 + lane * 4);
        x2[0] = bf2f(u.x); x2[1] = bf2f(u.y); x2[2] = bf2f(u.z); x2[3] = bf2f(u.w);
    }
    const float4 a4 = *(const float4*)(pa + lane * 4);
    const float aa[4] = {a4.x, a4.y, a4.z, a4.w};
    ushort4 o;
    unsigned short* op = (unsigned short*)&o;
#pragma unroll
    for (int i = 0; i < 4; i++) {
        float r = fmaf(k0, x0[i], fmaf(k1, x1[i], k2 * x2[i]));
        r = r >= 0.f ? r : aa[i] * r;
        op[i] = f2bf(r);
    }
    *(ushort4*)(out + row * 256 + lane * 4) = o;
}

// ---------------------------------------------------------------------------
// Transposed conv from bf16 masked. Wave per output sample; shuffle reduce.
// ---------------------------------------------------------------------------
__global__ __launch_bounds__(256) void k_deconv(const unsigned short* __restrict__ masked,
                                                const float* __restrict__ dwT,
                                                void* dout, const unsigned* probe) {
    const int wave = threadIdx.x >> 6, lane = threadIdx.x & 63;
    const int tt = blockIdx.x * 4 + wave;
    const int b = blockIdx.y;
    const int j0 = tt & 7, l0 = tt >> 3;
    float s = 0.f;
    if (l0 < LF) {
        const ushort4 u = *(const ushort4*)(masked + ((long long)b * LF + l0) * 256 + lane * 4);
        const float4 w = *(const float4*)(dwT + j0 * 256 + lane * 4);
        s = fmaf(bf2f(u.x), w.x, fmaf(bf2f(u.y), w.y, fmaf(bf2f(u.z), w.z, bf2f(u.w) * w.w)));
    }
    if (l0 >= 1) {
        const ushort4 u = *(const ushort4*)(masked + ((long long)b * LF + l0 - 1) * 256 + lane * 4);
        const float4 w = *(const float4*)(dwT + (j0 + 8) * 256 + lane * 4);
        s += fmaf(bf2f(u.x), w.x, fmaf(bf2f(u.y), w.y, fmaf(bf2f(u.z), w.z, bf2f(u.w) * w.w)));
    }
#pragma unroll
    for (int off = 32; off; off >>= 1) s += __shfl_xor(s, off, 64);
    if (lane == 0) {
        if (*probe == 0x3F803F80u) ((__hip_bfloat16*)dout)[(long long)b * SEQLEN + tt] = __float2bfloat16(s);
        else                       ((float*)dout)[(long long)b * SEQLEN + tt] = s;
    }
}

// ---------------------------------------------------------------------------
// Host launch
// ---------------------------------------------------------------------------
extern "C" void kernel_launch(void* const* d_in, const int* in_sizes, int n_in,
                              void* d_out, int out_size, void* d_ws, size_t ws_size,
                              hipStream_t stream) {
    float* W = (float*)d_ws;
    const unsigned* probe = (const unsigned*)d_in[4];  // me_ln_g (all ones)

    static const long long O[21] = {
        0, 131072, 262144, 266240, 270336, 270592, 270848, 336384, 336640, 337664,
        338688, 338692, 535300, 536068, 538372, 538408, 541480, 803624, 804648,
        870184, 870440
    };
    const long long ACWT = 874560, BCWT = 878656, DWT = 882752;
    const long long ENC = 886848;                     // f32, 16384*256
    const long long KER = ENC + 4194304;              // f32, 16380*3
    const long long FEND = KER + 49152;               // (49140 rounded up, keeps align)
    unsigned short* H = (unsigned short*)(W + FEND);  // bf16 arena
    const long long WB_INIT = 0;                      // 65536
    const long long WB_FINAL = 65536;                 // 65536
    const long long WB_SKIP = 131072;                 // 4 x 65536
    const long long WB_INV1 = 393216;                 // 12 x 16384
    const long long B_T1 = 589824;                    // bf16 bufs: 16384*256 each
    const long long B_T2 = B_T1 + 4194304;
    const long long B_T3 = B_T2 + 4194304;
    const long long B_T4 = B_T3 + 4194304;
    const long long B_T5 = B_T4 + 4194304;            // masked

    CvtArgs ca;
    for (int i = 0; i < 21; i++) { ca.src[i] = d_in[i]; ca.off[i] = O[i]; ca.n[i] = in_sizes[i]; }
    k_convert<<<dim3(256, 21), 256, 0, stream>>>(ca, W, probe);

    CastArgs cs;
    cs.soff[0] = O[6];  cs.doff[0] = WB_INIT;  cs.n[0] = 65536;
    cs.soff[1] = O[18]; cs.doff[1] = WB_FINAL; cs.n[1] = 65536;
    cs.soff[2] = O[16]; cs.doff[2] = WB_SKIP;  cs.n[2] = 262144;
    cs.soff[3] = O[11]; cs.doff[3] = WB_INV1;  cs.n[3] = 196608;
    k_cast<<<dim3(64, 4), 256, 0, stream>>>(cs, W, H);

    TrArgs ta;
    ta.e[0] = {O[2],  ACWT, 256, 16};
    ta.e[1] = {O[3],  BCWT, 256, 16};
    ta.e[2] = {O[20], DWT,  256, 16};
    k_transpose<<<dim3(16, 3), 256, 0, stream>>>(ta, W);

    k_encoder<<<dim3(512, 4), 256, 0, stream>>>(W + O[0], W + O[1], W + ACWT, W + BCWT, W + ENC);

    k_ln<<<LF, 256, 0, stream>>>(W + ENC, 1, H + B_T1, W + O[4], W + O[5], nullptr);

    k_gemm<<<dim3(128, 4), 256, 0, stream>>>(H + B_T1, H + WB_INIT, W + O[7],
                                             nullptr, nullptr, 0, H + B_T2, 256);

    for (int b = 0; b < 4; b++) {
        k_ln<<<LF, 256, 0, stream>>>(H + B_T2, 0, H + B_T1, W + O[8] + b * 256, W + O[9] + b * 256, W + O[10] + b);

        long long src = B_T1;
        const long long dsts[3] = {B_T3, B_T4, B_T3};
        for (int p = 0; p < 3; p++) {
            const int bp = b * 3 + p;
            k_pw_ker<<<128, 256, 0, stream>>>(H + src, H + WB_INV1 + (long long)bp * 16384,
                                              W + O[12] + bp * 64, W + O[13] + bp * 192,
                                              W + O[14] + bp * 3, W + KER);
            k_apply<<<dim3(1024, 4), 256, 0, stream>>>(H + src, W + KER, W + O[15] + bp * 256, H + dsts[p]);
            src = dsts[p];
        }
        k_gemm<<<dim3(128, 4), 256, 0, stream>>>(H + B_T1, H + WB_SKIP + (long long)b * 65536,
                                                 W + O[17] + b * 256, H + B_T3, nullptr, 0, H + B_T2, 256);
    }

    k_gemm<<<dim3(128, 4), 256, 0, stream>>>(H + B_T2, H + WB_FINAL, W + O[19],
                                             nullptr, W + ENC, 1, H + B_T5, 256);

    k_deconv<<<dim3(8192, 4), 256, 0, stream>>>(H + B_T5, W + DWT, d_out, probe);
}

// Round 4
// 434.965 us; speedup vs baseline: 4.3148x; 1.0479x over previous
//
#include <hip/hip_runtime.h>
#include <hip/hip_bf16.h>

// ---- problem constants ----
#define LF 4095              // encoder output length: (32768-16)/8 + 1
#define SEQLEN 32768
#define NBATCH 4
#define MTOT (NBATCH * LF)   // 16380 trunk rows, layout [m][256] channels-last

typedef __attribute__((ext_vector_type(8))) short short8;   // 8 bf16 (4 VGPRs)
typedef __attribute__((ext_vector_type(4))) float f32x4;

__device__ __forceinline__ float bf2f(unsigned short u) {
    return __uint_as_float(((unsigned)u) << 16);
}
__device__ __forceinline__ unsigned short f2bf(float f) {   // round-nearest-even
    unsigned u = __float_as_uint(f);
    return (unsigned short)((u + 0x7FFFu + ((u >> 16) & 1u)) >> 16);
}

// ---------------------------------------------------------------------------
// Input conversion with runtime dtype probe (me_ln_g is all 1.0):
//   f32 -> 0x3F800000 ; bf16 -> 0x3F803F80
// ---------------------------------------------------------------------------
struct CvtArgs { const void* src[21]; long long off[21]; int n[21]; };

__global__ __launch_bounds__(256) void k_convert(CvtArgs a, float* ws, const unsigned* probe) {
    const bool bf = (*probe == 0x3F803F80u);
    const int t = blockIdx.y;
    const int n = a.n[t];
    const float* sf = (const float*)a.src[t];
    const unsigned short* sh = (const unsigned short*)a.src[t];
    float* d = ws + a.off[t];
    for (int i = blockIdx.x * blockDim.x + threadIdx.x; i < n; i += gridDim.x * blockDim.x) {
        d[i] = bf ? bf2f(sh[i]) : sf[i];
    }
}

// f32 staged weights -> bf16 arena
struct CastArgs { long long soff[4], doff[4]; int n[4]; };

__global__ __launch_bounds__(256) void k_cast(CastArgs a, const float* Wf, unsigned short* H) {
    const int e = blockIdx.y;
    const int n = a.n[e];
    const float* s = Wf + a.soff[e];
    unsigned short* d = H + a.doff[e];
    for (int i = blockIdx.x * blockDim.x + threadIdx.x; i < n; i += gridDim.x * blockDim.x)
        d[i] = f2bf(s[i]);
}

// ---------------------------------------------------------------------------
// Small transposes: src [R][C] -> dst [C][R]  (conv weights to tap-major)
// ---------------------------------------------------------------------------
struct TrEntry { long long soff, doff; int R, C; };
struct TrArgs { TrEntry e[3]; };

__global__ __launch_bounds__(256) void k_transpose(TrArgs a, float* ws) {
    const TrEntry e = a.e[blockIdx.y];
    const int total = e.R * e.C;
    for (int i = blockIdx.x * blockDim.x + threadIdx.x; i < total; i += gridDim.x * blockDim.x) {
        const int r = i / e.C;
        const int c = i - r * e.C;
        ws[e.doff + (long long)c * e.R + r] = ws[e.soff + i];
    }
}

// ---------------------------------------------------------------------------
// Encoder + fused "me" LayerNorm.
// Block: 256 threads = channels; 8 l-rows per block. Writes raw enc (f32, for
// the final mask multiply) and LN(enc) (bf16 trunk input).
// grid (512, 4).
// ---------------------------------------------------------------------------
__global__ __launch_bounds__(256) void k_encoder_ln(
    const float* __restrict__ ac, const float* __restrict__ bc,
    const float* __restrict__ wTa, const float* __restrict__ wTb,
    const float* __restrict__ g, const float* __restrict__ be,
    float* __restrict__ enc, unsigned short* __restrict__ xout)
{
    __shared__ float E[8][260];
    const int c = threadIdx.x;
    const int b = blockIdx.y;
    const int l0 = blockIdx.x * 8;
    float wa[16], wb[16];
#pragma unroll
    for (int t = 0; t < 16; t++) { wa[t] = wTa[t * 256 + c]; wb[t] = wTb[t * 256 + c]; }
#pragma unroll
    for (int dl = 0; dl < 8; dl++) {
        const int l = l0 + dl;
        float acc = 0.f;
        if (l < LF) {
            const float* pa = ac + (long long)b * SEQLEN + 8 * l;
            const float* pb = bc + (long long)b * SEQLEN + 8 * l;
#pragma unroll
            for (int t = 0; t < 16; t++) acc = fmaf(wa[t], pa[t], fmaf(wb[t], pb[t], acc));
            enc[((long long)b * LF + l) * 256 + c] = acc;
        }
        E[dl][c] = acc;
    }
    __syncthreads();
    const int w = threadIdx.x >> 6, lane = threadIdx.x & 63;
    const float4 g4 = *(const float4*)(g + lane * 4);
    const float4 b4 = *(const float4*)(be + lane * 4);
#pragma unroll
    for (int i = 0; i < 2; i++) {
        const int dl = w * 2 + i;
        const int l = l0 + dl;
        if (l >= LF) continue;
        const float4 v = *((const float4*)&E[dl][0] + lane);
        float s  = v.x + v.y + v.z + v.w;
        float ss = fmaf(v.x, v.x, fmaf(v.y, v.y, fmaf(v.z, v.z, v.w * v.w)));
#pragma unroll
        for (int off = 32; off; off >>= 1) { s += __shfl_xor(s, off, 64); ss += __shfl_xor(ss, off, 64); }
        const float mu = s * (1.f / 256.f);
        const float rs = rsqrtf(ss * (1.f / 256.f) - mu * mu + 1e-5f);
        ushort4 o;
        o.x = f2bf(fmaf((v.x - mu) * rs, g4.x, b4.x));
        o.y = f2bf(fmaf((v.y - mu) * rs, g4.y, b4.y));
        o.z = f2bf(fmaf((v.z - mu) * rs, g4.z, b4.z));
        o.w = f2bf(fmaf((v.w - mu) * rs, g4.w, b4.w));
        *(ushort4*)(xout + ((long long)b * LF + l) * 256 + lane * 4) = o;
    }
}

// ---------------------------------------------------------------------------
// Full-row bf16 MFMA GEMM (M=64/block, N=256, K=256) with fused epilogue:
//   v = A·Wt^T + bias [+ addsrc]; then either
//     prelu(act_a) + LayerNorm(ln_g, ln_b)    (trunk path)  or
//     relu + mulsrc(f32)                       (mask path)   or raw.
// A read ONCE (full-N block). LDS C round-trip gives whole rows per wave
// for the LN shuffle-reduce and coalesced bf16 stores. In-place A==out is
// safe: each block touches only its own 64 rows. grid 256.
// ---------------------------------------------------------------------------
__global__ __launch_bounds__(256) void k_gemm_fused(
    const unsigned short* __restrict__ A,
    const unsigned short* __restrict__ Wt,
    const float* __restrict__ bias,
    const unsigned short* __restrict__ addsrc,
    const float* __restrict__ act_a,
    const float* __restrict__ ln_g, const float* __restrict__ ln_b,
    const float* __restrict__ mulsrc, int relu,
    unsigned short* __restrict__ out)
{
    __shared__ __align__(16) char smem[66560];
    unsigned short (*As)[72] = (unsigned short(*)[72])smem;              //  9216 B
    unsigned short (*Bs)[72] = (unsigned short(*)[72])(smem + 9216);     // 36864 B
    float (*Cs)[260] = (float(*)[260])smem;                              // 66560 B overlay
    const int t = threadIdx.x;
    const int w = t >> 6, lane = t & 63;
    const int quad = lane >> 4, l16 = lane & 15;
    const int m0 = blockIdx.x * 64;
    f32x4 acc[4][4];
#pragma unroll
    for (int i = 0; i < 4; i++)
#pragma unroll
        for (int j = 0; j < 4; j++) acc[i][j] = (f32x4){0.f, 0.f, 0.f, 0.f};
    const int lr = t >> 3, lc = (t & 7) * 8;
    for (int k0 = 0; k0 < 256; k0 += 64) {
        __syncthreads();
#pragma unroll
        for (int it = 0; it < 2; it++) {
            const int r = lr + it * 32;
            long long gm = m0 + r; if (gm >= MTOT) gm = MTOT - 1;
            *(float4*)&As[r][lc] = *(const float4*)&A[gm * 256 + k0 + lc];
        }
#pragma unroll
        for (int it = 0; it < 8; it++) {
            const int r = lr + it * 32;
            *(float4*)&Bs[r][lc] = *(const float4*)&Wt[(long long)r * 256 + k0 + lc];
        }
        __syncthreads();
#pragma unroll
        for (int ks = 0; ks < 64; ks += 32) {
            short8 af[4], bfr[4];
#pragma unroll
            for (int i = 0; i < 4; i++) af[i] = *(const short8*)&As[i * 16 + l16][ks + quad * 8];
#pragma unroll
            for (int j = 0; j < 4; j++) bfr[j] = *(const short8*)&Bs[w * 64 + j * 16 + l16][ks + quad * 8];
#pragma unroll
            for (int i = 0; i < 4; i++)
#pragma unroll
                for (int j = 0; j < 4; j++)
                    acc[i][j] = __builtin_amdgcn_mfma_f32_16x16x32_bf16(af[i], bfr[j], acc[i][j], 0, 0, 0);
        }
    }
    __syncthreads();   // done with As/Bs; overlay Cs
#pragma unroll
    for (int i = 0; i < 4; i++)
#pragma unroll
        for (int j = 0; j < 4; j++)
#pragma unroll
            for (int r = 0; r < 4; r++)
                Cs[i * 16 + quad * 4 + r][w * 64 + j * 16 + l16] = acc[i][j][r];
    __syncthreads();
    const float4 bi4 = *(const float4*)(bias + lane * 4);
    float4 g4 = {0.f, 0.f, 0.f, 0.f}, b4 = {0.f, 0.f, 0.f, 0.f};
    if (ln_g) { g4 = *(const float4*)(ln_g + lane * 4); b4 = *(const float4*)(ln_b + lane * 4); }
    const float alpha = act_a ? *act_a : 0.f;
    for (int rr = 0; rr < 16; rr++) {
        const int row = w * 16 + rr;
        const int m = m0 + row;
        float4 v = *((const float4*)&Cs[row][0] + lane);
        v.x += bi4.x; v.y += bi4.y; v.z += bi4.z; v.w += bi4.w;
        if (addsrc) {
            const ushort4 u = *(const ushort4*)(addsrc + (long long)m * 256 + lane * 4);
            v.x += bf2f(u.x); v.y += bf2f(u.y); v.z += bf2f(u.z); v.w += bf2f(u.w);
        }
        if (act_a) {
            v.x = v.x < 0.f ? alpha * v.x : v.x;  v.y = v.y < 0.f ? alpha * v.y : v.y;
            v.z = v.z < 0.f ? alpha * v.z : v.z;  v.w = v.w < 0.f ? alpha * v.w : v.w;
        }
        if (ln_g) {
            float s  = v.x + v.y + v.z + v.w;
            float ss = fmaf(v.x, v.x, fmaf(v.y, v.y, fmaf(v.z, v.z, v.w * v.w)));
#pragma unroll
            for (int off = 32; off; off >>= 1) { s += __shfl_xor(s, off, 64); ss += __shfl_xor(ss, off, 64); }
            const float mu = s * (1.f / 256.f);
            const float rs = rsqrtf(ss * (1.f / 256.f) - mu * mu + 1e-5f);
            v.x = fmaf((v.x - mu) * rs, g4.x, b4.x);
            v.y = fmaf((v.y - mu) * rs, g4.y, b4.y);
            v.z = fmaf((v.z - mu) * rs, g4.z, b4.z);
            v.w = fmaf((v.w - mu) * rs, g4.w, b4.w);
        }
        if (relu) {
            v.x = fmaxf(v.x, 0.f); v.y = fmaxf(v.y, 0.f);
            v.z = fmaxf(v.z, 0.f); v.w = fmaxf(v.w, 0.f);
        }
        if (mulsrc) {
            const float4 mv = *(const float4*)(mulsrc + (long long)m * 256 + lane * 4);
            v.x *= mv.x; v.y *= mv.y; v.z *= mv.z; v.w *= mv.w;
        }
        if (m < MTOT) {
            ushort4 o;
            o.x = f2bf(v.x); o.y = f2bf(v.y); o.z = f2bf(v.z); o.w = f2bf(v.w);
            *(ushort4*)(out + (long long)m * 256 + lane * 4) = o;
        }
    }
}

// ---------------------------------------------------------------------------
// Fused involution stage: ker-gen (MFMA GEMM 64x64xK256 -> C in LDS ->
// w2 projection -> ker[64][3] in LDS) + involution apply + per-channel PReLU.
// src read-only, out separate (ping-pong). grid 256 blocks of 64 rows.
// ---------------------------------------------------------------------------
__global__ __launch_bounds__(256) void k_inv(
    const unsigned short* __restrict__ src,
    const unsigned short* __restrict__ W1,
    const float* __restrict__ b1, const float* __restrict__ w2,
    const float* __restrict__ b2, const float* __restrict__ pa,
    unsigned short* __restrict__ out)
{
    __shared__ __align__(16) char smem[18432];
    unsigned short (*As)[72] = (unsigned short(*)[72])smem;              // 9216 B
    unsigned short (*Bs)[72] = (unsigned short(*)[72])(smem + 9216);     // 9216 B
    float (*Cs)[68] = (float(*)[68])smem;                                // 17408 B overlay
    __shared__ float Ks[64][4];
    const int t = threadIdx.x;
    const int w = t >> 6, lane = t & 63;
    const int quad = lane >> 4, l16 = lane & 15;
    const int m0 = blockIdx.x * 64;
    f32x4 acc[4];
#pragma unroll
    for (int j = 0; j < 4; j++) acc[j] = (f32x4){0.f, 0.f, 0.f, 0.f};
    const int lr = t >> 3, lc = (t & 7) * 8;
    for (int k0 = 0; k0 < 256; k0 += 64) {
        __syncthreads();
#pragma unroll
        for (int it = 0; it < 2; it++) {
            const int r = lr + it * 32;
            long long gm = m0 + r; if (gm >= MTOT) gm = MTOT - 1;
            *(float4*)&As[r][lc] = *(const float4*)&src[gm * 256 + k0 + lc];
            *(float4*)&Bs[r][lc] = *(const float4*)&W1[(long long)r * 256 + k0 + lc];
        }
        __syncthreads();
#pragma unroll
        for (int ks = 0; ks < 64; ks += 32) {
            const short8 af = *(const short8*)&As[w * 16 + l16][ks + quad * 8];
#pragma unroll
            for (int j = 0; j < 4; j++) {
                const short8 bf = *(const short8*)&Bs[j * 16 + l16][ks + quad * 8];
                acc[j] = __builtin_amdgcn_mfma_f32_16x16x32_bf16(af, bf, acc[j], 0, 0, 0);
            }
        }
    }
    __syncthreads();   // done with As/Bs; overlay Cs
#pragma unroll
    for (int j = 0; j < 4; j++) {
        const float b1v = b1[j * 16 + l16];
#pragma unroll
        for (int r = 0; r < 4; r++)
            Cs[w * 16 + quad * 4 + r][j * 16 + l16] = acc[j][r] + b1v;
    }
    __syncthreads();
    if (t < 192) {
        const int ml = t & 63, k = t >> 6;
        float s = b2[k];
        const float* wr = w2 + k * 64;
#pragma unroll 8
        for (int o = 0; o < 64; o++) s = fmaf(wr[o], Cs[ml][o], s);
        Ks[ml][k] = s;
    }
    __syncthreads();
    const float4 pa4 = *(const float4*)(pa + lane * 4);
    const float aa[4] = {pa4.x, pa4.y, pa4.z, pa4.w};
    for (int rr = 0; rr < 16; rr++) {
        const int ml = w * 16 + rr;
        const int m = m0 + ml;
        if (m >= MTOT) break;
        const int bb = m / LF;
        const int l = m - bb * LF;
        const float k0v = Ks[ml][0], k1v = Ks[ml][1], k2v = Ks[ml][2];
        const long long base = (long long)m * 256 + lane * 4;
        const ushort4 u1 = *(const ushort4*)(src + base);
        float x1[4] = {bf2f(u1.x), bf2f(u1.y), bf2f(u1.z), bf2f(u1.w)};
        float x0[4] = {0.f, 0.f, 0.f, 0.f}, x2[4] = {0.f, 0.f, 0.f, 0.f};
        if (l > 0) {
            const ushort4 u = *(const ushort4*)(src + base - 256);
            x0[0] = bf2f(u.x); x0[1] = bf2f(u.y); x0[2] = bf2f(u.z); x0[3] = bf2f(u.w);
        }
        if (l < LF - 1) {
            const ushort4 u = *(const ushort4*)(src + base + 256);
            x2[0] = bf2f(u.x); x2[1] = bf2f(u.y); x2[2] = bf2f(u.z); x2[3] = bf2f(u.w);
        }
        ushort4 o;
        unsigned short* op = (unsigned short*)&o;
#pragma unroll
        for (int i = 0; i < 4; i++) {
            float r = fmaf(k0v, x0[i], fmaf(k1v, x1[i], k2v * x2[i]));
            r = r >= 0.f ? r : aa[i] * r;
            op[i] = f2bf(r);
        }
        *(ushort4*)(out + base) = o;
    }
}

// ---------------------------------------------------------------------------
// Transposed conv from bf16 masked. Wave per output sample; shuffle reduce.
// ---------------------------------------------------------------------------
__global__ __launch_bounds__(256) void k_deconv(const unsigned short* __restrict__ masked,
                                                const float* __restrict__ dwT,
                                                void* dout, const unsigned* probe) {
    const int wave = threadIdx.x >> 6, lane = threadIdx.x & 63;
    const int tt = blockIdx.x * 4 + wave;
    const int b = blockIdx.y;
    const int j0 = tt & 7, l0 = tt >> 3;
    float s = 0.f;
    if (l0 < LF) {
        const ushort4 u = *(const ushort4*)(masked + ((long long)b * LF + l0) * 256 + lane * 4);
        const float4 w = *(const float4*)(dwT + j0 * 256 + lane * 4);
        s = fmaf(bf2f(u.x), w.x, fmaf(bf2f(u.y), w.y, fmaf(bf2f(u.z), w.z, bf2f(u.w) * w.w)));
    }
    if (l0 >= 1) {
        const ushort4 u = *(const ushort4*)(masked + ((long long)b * LF + l0 - 1) * 256 + lane * 4);
        const float4 w = *(const float4*)(dwT + (j0 + 8) * 256 + lane * 4);
        s += fmaf(bf2f(u.x), w.x, fmaf(bf2f(u.y), w.y, fmaf(bf2f(u.z), w.z, bf2f(u.w) * w.w)));
    }
#pragma unroll
    for (int off = 32; off; off >>= 1) s += __shfl_xor(s, off, 64);
    if (lane == 0) {
        if (*probe == 0x3F803F80u) ((__hip_bfloat16*)dout)[(long long)b * SEQLEN + tt] = __float2bfloat16(s);
        else                       ((float*)dout)[(long long)b * SEQLEN + tt] = s;
    }
}

// ---------------------------------------------------------------------------
// Host launch
// ---------------------------------------------------------------------------
extern "C" void kernel_launch(void* const* d_in, const int* in_sizes, int n_in,
                              void* d_out, int out_size, void* d_ws, size_t ws_size,
                              hipStream_t stream) {
    float* W = (float*)d_ws;
    const unsigned* probe = (const unsigned*)d_in[4];  // me_ln_g (all ones)

    static const long long O[21] = {
        0, 131072, 262144, 266240, 270336, 270592, 270848, 336384, 336640, 337664,
        338688, 338692, 535300, 536068, 538372, 538408, 541480, 803624, 804648,
        870184, 870440
    };
    const long long ACWT = 874560, BCWT = 878656, DWT = 882752;
    const long long ENC = 886848;                     // f32 enc, 16384*256
    const long long FEND = ENC + 4194304;
    unsigned short* H = (unsigned short*)(W + FEND);  // bf16 arena
    const long long WB_INIT  = 0;                     // 65536
    const long long WB_FINAL = 65536;                 // 65536
    const long long WB_SKIP  = 131072;                // 4 x 65536
    const long long WB_INV1  = 393216;                // 12 x 16384
    const long long B_LN0    = 589824;                // trunk bufs: 16384*256 bf16 each
    const long long B_XN     = B_LN0 + 4194304;
    const long long B_M1     = B_XN  + 4194304;
    const long long B_M2     = B_M1  + 4194304;
    const long long B_X      = B_M2  + 4194304;
    const long long B_MASKED = B_X   + 4194304;

    CvtArgs ca;
    for (int i = 0; i < 21; i++) { ca.src[i] = d_in[i]; ca.off[i] = O[i]; ca.n[i] = in_sizes[i]; }
    k_convert<<<dim3(256, 21), 256, 0, stream>>>(ca, W, probe);

    CastArgs cs;
    cs.soff[0] = O[6];  cs.doff[0] = WB_INIT;  cs.n[0] = 65536;
    cs.soff[1] = O[18]; cs.doff[1] = WB_FINAL; cs.n[1] = 65536;
    cs.soff[2] = O[16]; cs.doff[2] = WB_SKIP;  cs.n[2] = 262144;
    cs.soff[3] = O[11]; cs.doff[3] = WB_INV1;  cs.n[3] = 196608;
    k_cast<<<dim3(64, 4), 256, 0, stream>>>(cs, W, H);

    TrArgs ta;
    ta.e[0] = {O[2],  ACWT, 256, 16};
    ta.e[1] = {O[3],  BCWT, 256, 16};
    ta.e[2] = {O[20], DWT,  256, 16};
    k_transpose<<<dim3(16, 3), 256, 0, stream>>>(ta, W);

    // encoder + me-LN: enc(f32) and LN(enc)(bf16)
    k_encoder_ln<<<dim3(512, 4), 256, 0, stream>>>(W + O[0], W + O[1], W + ACWT, W + BCWT,
                                                   W + O[4], W + O[5], W + ENC, H + B_LN0);

    // me_init GEMM + prelu(a0) + LN(g0,b0) -> xn_0
    k_gemm_fused<<<256, 256, 0, stream>>>(H + B_LN0, H + WB_INIT, W + O[7],
                                          nullptr, W + O[10] + 0, W + O[8], W + O[9],
                                          nullptr, 0, H + B_XN);

    for (int b = 0; b < 4; b++) {
        const long long srcs[3] = {B_XN, B_M1, B_M2};
        const long long dsts[3] = {B_M1, B_M2, B_M1};
        for (int p = 0; p < 3; p++) {
            const int bp = b * 3 + p;
            k_inv<<<256, 256, 0, stream>>>(H + srcs[p], H + WB_INV1 + (long long)bp * 16384,
                                           W + O[12] + bp * 64, W + O[13] + bp * 192,
                                           W + O[14] + bp * 3, W + O[15] + bp * 256, H + dsts[p]);
        }
        if (b < 3) {
            // x_{b+1} = m + skip(xn_b) ; fused prelu(a_{b+1}) + LN(g_{b+1}) -> xn_{b+1}
            k_gemm_fused<<<256, 256, 0, stream>>>(H + B_XN, H + WB_SKIP + (long long)b * 65536,
                                                  W + O[17] + b * 256, H + B_M1,
                                                  W + O[10] + b + 1,
                                                  W + O[8] + (b + 1) * 256, W + O[9] + (b + 1) * 256,
                                                  nullptr, 0, H + B_XN);
        } else {
            // x_3 raw
            k_gemm_fused<<<256, 256, 0, stream>>>(H + B_XN, H + WB_SKIP + (long long)b * 65536,
                                                  W + O[17] + b * 256, H + B_M1,
                                                  nullptr, nullptr, nullptr,
                                                  nullptr, 0, H + B_X);
        }
    }

    // masked = enc * relu(me_final(x_3))
    k_gemm_fused<<<256, 256, 0, stream>>>(H + B_X, H + WB_FINAL, W + O[19],
                                          nullptr, nullptr, nullptr, nullptr,
                                          W + ENC, 1, H + B_MASKED);

    k_deconv<<<dim3(8192, 4), 256, 0, stream>>>(H + B_MASKED, W + DWT, d_out, probe);
}

// Round 5
// 278.261 us; speedup vs baseline: 6.7447x; 1.5632x over previous
//
#include <hip/hip_runtime.h>
#include <hip/hip_bf16.h>

// ---- problem constants ----
#define LF 4095              // encoder output length: (32768-16)/8 + 1
#define SEQLEN 32768
#define MTOT 16380           // 4*4095 trunk rows, layout [m][256] channels-last

typedef __attribute__((ext_vector_type(8))) short short8;   // 8 bf16 (4 VGPRs)
typedef __attribute__((ext_vector_type(4))) float f32x4;

__device__ __forceinline__ float bf2f(unsigned short u) {
    return __uint_as_float(((unsigned)u) << 16);
}
__device__ __forceinline__ unsigned short f2bf(float f) {   // round-nearest-even
    unsigned u = __float_as_uint(f);
    return (unsigned short)((u + 0x7FFFu + ((u >> 16) & 1u)) >> 16);
}

// ---------------------------------------------------------------------------
// One-launch prep. Phases (blockIdx.y), all reading d_in directly:
//  kind 0: convert -> f32 arena        kind 1: cast -> bf16 arena
//  kind 2: transpose [256][16]->[16][256] f32   kind 3: same -> bf16
// dtype probe: me_ln_g all-ones: f32 0x3F800000, bf16 0x3F803F80.
// ---------------------------------------------------------------------------
struct PrepArgs { const void* src[28]; long long off[28]; int n[28]; int kind[28]; };

__global__ __launch_bounds__(256) void k_prep(PrepArgs a, float* W, unsigned short* H,
                                              const unsigned* probe) {
    const bool bf = (*probe == 0x3F803F80u);
    const int ph = blockIdx.y;
    const int kind = a.kind[ph];
    const int n = a.n[ph];
    const float* sf = (const float*)a.src[ph];
    const unsigned short* sh = (const unsigned short*)a.src[ph];
    for (int i = blockIdx.x * 256 + threadIdx.x; i < n; i += gridDim.x * 256) {
        const float v = bf ? bf2f(sh[i]) : sf[i];
        if (kind == 0) {
            W[a.off[ph] + i] = v;
        } else if (kind == 1) {
            H[a.off[ph] + i] = bf ? sh[i] : f2bf(v);
        } else {
            const int r = i >> 4, c = i & 15;
            const long long d = a.off[ph] + (long long)c * 256 + r;
            if (kind == 2) W[d] = v;
            else           H[d] = f2bf(v);
        }
    }
}

// ---------------------------------------------------------------------------
// Encoder + fused "me" LayerNorm. Block: 256 threads = channels; 8 l-rows.
// Writes enc (bf16, for final mask multiply) and LN(enc) (bf16 trunk input).
// grid (512, 4).
// ---------------------------------------------------------------------------
__global__ __launch_bounds__(256) void k_encoder_ln(
    const float* __restrict__ ac, const float* __restrict__ bc,
    const float* __restrict__ wTa, const float* __restrict__ wTb,
    const float* __restrict__ g, const float* __restrict__ be,
    unsigned short* __restrict__ enc, unsigned short* __restrict__ xout)
{
    __shared__ float E[8][260];
    const int c = threadIdx.x;
    const int b = blockIdx.y;
    const int l0 = blockIdx.x * 8;
    float wa[16], wb[16];
#pragma unroll
    for (int t = 0; t < 16; t++) { wa[t] = wTa[t * 256 + c]; wb[t] = wTb[t * 256 + c]; }
#pragma unroll
    for (int dl = 0; dl < 8; dl++) {
        const int l = l0 + dl;
        float acc = 0.f;
        if (l < LF) {
            const float* pa = ac + (long long)b * SEQLEN + 8 * l;
            const float* pb = bc + (long long)b * SEQLEN + 8 * l;
#pragma unroll
            for (int t = 0; t < 16; t++) acc = fmaf(wa[t], pa[t], fmaf(wb[t], pb[t], acc));
            enc[((long long)b * LF + l) * 256 + c] = f2bf(acc);
        }
        E[dl][c] = acc;
    }
    __syncthreads();
    const int w = threadIdx.x >> 6, lane = threadIdx.x & 63;
    const float4 g4 = *(const float4*)(g + lane * 4);
    const float4 b4 = *(const float4*)(be + lane * 4);
#pragma unroll
    for (int i = 0; i < 2; i++) {
        const int dl = w * 2 + i;
        const int l = l0 + dl;
        if (l >= LF) continue;
        const float4 v = *((const float4*)&E[dl][0] + lane);
        float s  = v.x + v.y + v.z + v.w;
        float ss = fmaf(v.x, v.x, fmaf(v.y, v.y, fmaf(v.z, v.z, v.w * v.w)));
#pragma unroll
        for (int off = 32; off; off >>= 1) { s += __shfl_xor(s, off, 64); ss += __shfl_xor(ss, off, 64); }
        const float mu = s * (1.f / 256.f);
        const float rs = rsqrtf(ss * (1.f / 256.f) - mu * mu + 1e-5f);
        ushort4 o;
        o.x = f2bf(fmaf((v.x - mu) * rs, g4.x, b4.x));
        o.y = f2bf(fmaf((v.y - mu) * rs, g4.y, b4.y));
        o.z = f2bf(fmaf((v.z - mu) * rs, g4.z, b4.z));
        o.w = f2bf(fmaf((v.w - mu) * rs, g4.w, b4.w));
        *(ushort4*)(xout + ((long long)b * LF + l) * 256 + lane * 4) = o;
    }
}

// ---------------------------------------------------------------------------
// bf16 MFMA GEMM, M=32/block, N=256 (full row), K=256, fused epilogue:
//   v = A·Wt^T + bias [+ addsrc(bf16)]; then prelu+LN, or relu+mul(bf16), or raw.
// LDS 41.5 KB (Cs overlays As+Bs) -> 2 blocks/CU at grid 512.
// In-place A==out safe (block reads only its own rows; all reads precede stores).
// ---------------------------------------------------------------------------
__global__ __launch_bounds__(256) void k_gemm_fused(
    const unsigned short* __restrict__ A,
    const unsigned short* __restrict__ Wt,
    const float* __restrict__ bias,
    const unsigned short* __restrict__ addsrc,
    const float* __restrict__ act_a,
    const float* __restrict__ ln_g, const float* __restrict__ ln_b,
    const unsigned short* __restrict__ mulsrc, int relu,
    unsigned short* __restrict__ out)
{
    __shared__ __align__(16) char smem[41472];
    unsigned short (*As)[72] = (unsigned short(*)[72])smem;              //  4608 B
    unsigned short (*Bs)[72] = (unsigned short(*)[72])(smem + 4608);     // 36864 B
    float (*Cs)[260] = (float(*)[260])smem;                              // 33280 B overlay
    const int t = threadIdx.x;
    const int w = t >> 6, lane = t & 63;
    const int quad = lane >> 4, l16 = lane & 15;
    const int m0 = blockIdx.x * 32;
    f32x4 acc[2][4];
#pragma unroll
    for (int i = 0; i < 2; i++)
#pragma unroll
        for (int j = 0; j < 4; j++) acc[i][j] = (f32x4){0.f, 0.f, 0.f, 0.f};
    const int lr = t >> 3, lc = (t & 7) * 8;
    for (int k0 = 0; k0 < 256; k0 += 64) {
        __syncthreads();
        {
            long long gm = m0 + lr; if (gm >= MTOT) gm = MTOT - 1;
            *(float4*)&As[lr][lc] = *(const float4*)&A[gm * 256 + k0 + lc];
        }
#pragma unroll
        for (int it = 0; it < 8; it++) {
            const int r = lr + it * 32;
            *(float4*)&Bs[r][lc] = *(const float4*)&Wt[(long long)r * 256 + k0 + lc];
        }
        __syncthreads();
#pragma unroll
        for (int ks = 0; ks < 2; ks++) {
            short8 af[2], bfr[4];
#pragma unroll
            for (int i = 0; i < 2; i++) af[i] = *(const short8*)&As[i * 16 + l16][ks * 32 + quad * 8];
#pragma unroll
            for (int j = 0; j < 4; j++) bfr[j] = *(const short8*)&Bs[w * 64 + j * 16 + l16][ks * 32 + quad * 8];
#pragma unroll
            for (int i = 0; i < 2; i++)
#pragma unroll
                for (int j = 0; j < 4; j++)
                    acc[i][j] = __builtin_amdgcn_mfma_f32_16x16x32_bf16(af[i], bfr[j], acc[i][j], 0, 0, 0);
        }
    }
    __syncthreads();   // As/Bs dead; overlay Cs
#pragma unroll
    for (int i = 0; i < 2; i++)
#pragma unroll
        for (int j = 0; j < 4; j++)
#pragma unroll
            for (int r = 0; r < 4; r++)
                Cs[i * 16 + quad * 4 + r][w * 64 + j * 16 + l16] = acc[i][j][r];
    __syncthreads();
    const float4 bi4 = *(const float4*)(bias + lane * 4);
    float4 g4 = {0.f, 0.f, 0.f, 0.f}, b4 = {0.f, 0.f, 0.f, 0.f};
    if (ln_g) { g4 = *(const float4*)(ln_g + lane * 4); b4 = *(const float4*)(ln_b + lane * 4); }
    const float alpha = act_a ? *act_a : 0.f;
#pragma unroll
    for (int rr = 0; rr < 8; rr++) {
        const int row = w * 8 + rr;
        const int m = m0 + row;
        float4 v = *((const float4*)&Cs[row][0] + lane);
        v.x += bi4.x; v.y += bi4.y; v.z += bi4.z; v.w += bi4.w;
        if (addsrc) {
            const ushort4 u = *(const ushort4*)(addsrc + (long long)m * 256 + lane * 4);
            v.x += bf2f(u.x); v.y += bf2f(u.y); v.z += bf2f(u.z); v.w += bf2f(u.w);
        }
        if (act_a) {
            v.x = v.x < 0.f ? alpha * v.x : v.x;  v.y = v.y < 0.f ? alpha * v.y : v.y;
            v.z = v.z < 0.f ? alpha * v.z : v.z;  v.w = v.w < 0.f ? alpha * v.w : v.w;
        }
        if (ln_g) {
            float s  = v.x + v.y + v.z + v.w;
            float ss = fmaf(v.x, v.x, fmaf(v.y, v.y, fmaf(v.z, v.z, v.w * v.w)));
#pragma unroll
            for (int off = 32; off; off >>= 1) { s += __shfl_xor(s, off, 64); ss += __shfl_xor(ss, off, 64); }
            const float mu = s * (1.f / 256.f);
            const float rs = rsqrtf(ss * (1.f / 256.f) - mu * mu + 1e-5f);
            v.x = fmaf((v.x - mu) * rs, g4.x, b4.x);
            v.y = fmaf((v.y - mu) * rs, g4.y, b4.y);
            v.z = fmaf((v.z - mu) * rs, g4.z, b4.z);
            v.w = fmaf((v.w - mu) * rs, g4.w, b4.w);
        }
        if (relu) {
            v.x = fmaxf(v.x, 0.f); v.y = fmaxf(v.y, 0.f);
            v.z = fmaxf(v.z, 0.f); v.w = fmaxf(v.w, 0.f);
        }
        if (mulsrc) {
            const ushort4 u = *(const ushort4*)(mulsrc + (long long)m * 256 + lane * 4);
            v.x *= bf2f(u.x); v.y *= bf2f(u.y); v.z *= bf2f(u.z); v.w *= bf2f(u.w);
        }
        if (m < MTOT) {
            ushort4 o;
            o.x = f2bf(v.x); o.y = f2bf(v.y); o.z = f2bf(v.z); o.w = f2bf(v.w);
            *(ushort4*)(out + (long long)m * 256 + lane * 4) = o;
        }
    }
}

// ---------------------------------------------------------------------------
// Fused involution stage, M=32/block, grid 512 (~61 KB LDS -> 2 blocks/CU):
// stage W1(64x256) + A rows [m0-1, m0+33) once; MFMA 32x64xK256; C+b1 -> LDS;
// w2 projection -> ker[32][3]; apply (+per-ch PReLU) reading neighbors from LDS.
// ---------------------------------------------------------------------------
__global__ __launch_bounds__(256) void k_inv(
    const unsigned short* __restrict__ src,
    const unsigned short* __restrict__ W1,
    const float* __restrict__ b1, const float* __restrict__ w2,
    const float* __restrict__ b2, const float* __restrict__ pa,
    unsigned short* __restrict__ out)
{
    __shared__ __align__(16) unsigned short W1s[64][264];  // 33792 B
    __shared__ __align__(16) unsigned short As[34][264];   // 17952 B
    __shared__ float Cs[32][68];                           //  8704 B
    __shared__ float Ks[32][4];
    const int t = threadIdx.x;
    const int w = t >> 6, lane = t & 63;
    const int quad = lane >> 4, l16 = lane & 15;
    const int m0 = blockIdx.x * 32;
    const int lr = t >> 3, lcb = (t & 7) * 8;
#pragma unroll
    for (int it = 0; it < 2; it++) {
        const int r = lr + it * 32;
#pragma unroll
        for (int jc = 0; jc < 4; jc++)
            *(float4*)&W1s[r][lcb + jc * 64] = *(const float4*)&W1[(long long)r * 256 + lcb + jc * 64];
    }
    for (int r = lr; r < 34; r += 32) {
        long long gm = (long long)m0 - 1 + r;
        gm = gm < 0 ? 0 : (gm >= MTOT ? MTOT - 1 : gm);
#pragma unroll
        for (int jc = 0; jc < 4; jc++)
            *(float4*)&As[r][lcb + jc * 64] = *(const float4*)&src[gm * 256 + lcb + jc * 64];
    }
    __syncthreads();
    // MFMA: wave w -> M-half mi = w&1, N-half nb = (w>>1)*32
    const int mi = w & 1, nb = (w >> 1) * 32;
    f32x4 acc[2];
    acc[0] = (f32x4){0.f, 0.f, 0.f, 0.f};
    acc[1] = (f32x4){0.f, 0.f, 0.f, 0.f};
#pragma unroll
    for (int ks = 0; ks < 8; ks++) {
        const short8 af = *(const short8*)&As[1 + mi * 16 + l16][ks * 32 + quad * 8];
#pragma unroll
        for (int j = 0; j < 2; j++) {
            const short8 bfr = *(const short8*)&W1s[nb + j * 16 + l16][ks * 32 + quad * 8];
            acc[j] = __builtin_amdgcn_mfma_f32_16x16x32_bf16(af, bfr, acc[j], 0, 0, 0);
        }
    }
#pragma unroll
    for (int j = 0; j < 2; j++) {
        const int o = nb + j * 16 + l16;
        const float b1v = b1[o];
#pragma unroll
        for (int r = 0; r < 4; r++)
            Cs[mi * 16 + quad * 4 + r][o] = acc[j][r] + b1v;
    }
    __syncthreads();
    if (t < 96) {
        const int r = t & 31, k = t >> 5;
        float s = b2[k];
        const float* wr = w2 + k * 64;
#pragma unroll 8
        for (int o = 0; o < 64; o++) s = fmaf(wr[o], Cs[r][o], s);
        Ks[r][k] = s;
    }
    __syncthreads();
    // apply: row r = t>>3, 8 threads per row over channels
    const int r = t >> 3;
    const int m = m0 + r;
    if (m < MTOT) {
        const int bb = m / LF;
        const int l = m - bb * LF;
        const float k0v = Ks[r][0], k1v = Ks[r][1], k2v = Ks[r][2];
        const bool hasL = (l > 0), hasR = (l < LF - 1);
#pragma unroll
        for (int j = 0; j < 8; j++) {
            const int ch = ((t & 7) + 8 * j) * 4;
            const ushort4 u1 = *(const ushort4*)&As[r + 1][ch];
            const ushort4 u0 = *(const ushort4*)&As[r][ch];
            const ushort4 u2 = *(const ushort4*)&As[r + 2][ch];
            const float4 a4 = *(const float4*)(pa + ch);
            float x0[4] = {hasL ? bf2f(u0.x) : 0.f, hasL ? bf2f(u0.y) : 0.f,
                           hasL ? bf2f(u0.z) : 0.f, hasL ? bf2f(u0.w) : 0.f};
            float x2[4] = {hasR ? bf2f(u2.x) : 0.f, hasR ? bf2f(u2.y) : 0.f,
                           hasR ? bf2f(u2.z) : 0.f, hasR ? bf2f(u2.w) : 0.f};
            const float x1[4] = {bf2f(u1.x), bf2f(u1.y), bf2f(u1.z), bf2f(u1.w)};
            const float aa[4] = {a4.x, a4.y, a4.z, a4.w};
            ushort4 o;
            unsigned short* op = (unsigned short*)&o;
#pragma unroll
            for (int i = 0; i < 4; i++) {
                float v = fmaf(k0v, x0[i], fmaf(k1v, x1[i], k2v * x2[i]));
                v = v >= 0.f ? v : aa[i] * v;
                op[i] = f2bf(v);
            }
            *(ushort4*)&out[(long long)m * 256 + ch] = o;
        }
    }
}

// ---------------------------------------------------------------------------
// Deconv as MFMA GEMM: C[l][n] = masked[l]·Wcat[n], n=0..15 where
// Wcat[n][c]=dec_w[c][n]. out[b, 8*l0+j] = C[l0][j] + C[l0-1][j+8] with edge
// masking. Block: 32 out-rows, stages masked rows [lo-1, lo+47) (clamped).
// grid 512 (tiles aligned to 4096-row batches).
// ---------------------------------------------------------------------------
__global__ __launch_bounds__(256) void k_deconv(
    const unsigned short* __restrict__ masked, const unsigned short* __restrict__ Wc,
    void* dout, const unsigned* probe)
{
    __shared__ __align__(16) unsigned short As[48][264];  // 25344 B
    __shared__ __align__(16) unsigned short Bs[16][264];  //  8448 B
    __shared__ float Csd[48][20];                         //  3840 B
    const int t = threadIdx.x;
    const int w = t >> 6, lane = t & 63;
    const int quad = lane >> 4, l16 = lane & 15;
    const int g0 = blockIdx.x * 32;
    const int b = g0 >> 12;
    const int lo = g0 & 4095;
    const int lr = t >> 3, lcb = (t & 7) * 8;
    for (int r = lr; r < 48; r += 32) {
        int ml = lo - 1 + r; ml = ml < 0 ? 0 : (ml > LF - 1 ? LF - 1 : ml);
        const long long gm = (long long)b * LF + ml;
#pragma unroll
        for (int jc = 0; jc < 4; jc++)
            *(float4*)&As[r][lcb + jc * 64] = *(const float4*)&masked[gm * 256 + lcb + jc * 64];
    }
    if (lr < 16) {
#pragma unroll
        for (int jc = 0; jc < 4; jc++)
            *(float4*)&Bs[lr][lcb + jc * 64] = *(const float4*)&Wc[(long long)lr * 256 + lcb + jc * 64];
    }
    __syncthreads();
    if (w < 3) {
        f32x4 acc = (f32x4){0.f, 0.f, 0.f, 0.f};
#pragma unroll
        for (int ks = 0; ks < 8; ks++) {
            const short8 af = *(const short8*)&As[w * 16 + l16][ks * 32 + quad * 8];
            const short8 bfr = *(const short8*)&Bs[l16][ks * 32 + quad * 8];
            acc = __builtin_amdgcn_mfma_f32_16x16x32_bf16(af, bfr, acc, 0, 0, 0);
        }
#pragma unroll
        for (int r = 0; r < 4; r++) Csd[w * 16 + quad * 4 + r][l16] = acc[r];
    }
    __syncthreads();
    const int i = t >> 3, j = t & 7;
    const int l0 = lo + i;
    float v = 0.f;
    if (l0 < LF) v = Csd[i + 1][j];
    if (l0 >= 1) v += Csd[i][j + 8];
    const long long oidx = (long long)b * SEQLEN + l0 * 8 + j;
    if (*probe == 0x3F803F80u) ((__hip_bfloat16*)dout)[oidx] = __float2bfloat16(v);
    else                       ((float*)dout)[oidx] = v;
}

// ---------------------------------------------------------------------------
// Host launch (21 launches)
// ---------------------------------------------------------------------------
extern "C" void kernel_launch(void* const* d_in, const int* in_sizes, int n_in,
                              void* d_out, int out_size, void* d_ws, size_t ws_size,
                              hipStream_t stream) {
    float* W = (float*)d_ws;
    const unsigned* probe = (const unsigned*)d_in[4];  // me_ln_g (all ones)

    static const long long O[21] = {
        0, 131072, 262144, 266240, 270336, 270592, 270848, 336384, 336640, 337664,
        338688, 338692, 535300, 536068, 538372, 538408, 541480, 803624, 804648,
        870184, 870440
    };
    const long long ACWT = 874560, BCWT = 878656;
    const long long FEND = 882752;
    unsigned short* H = (unsigned short*)(W + FEND);  // bf16 arena (element offsets)
    const long long WB_INIT  = 0;                     // 65536
    const long long WB_FINAL = 65536;                 // 65536
    const long long WB_SKIP  = 131072;                // 4 x 65536
    const long long WB_INV1  = 393216;                // 12 x 16384
    const long long WB_DEC   = 589824;                // 4096 (Wcat bf16 [16][256])
    const long long B_ENC    = 593920;                // trunk bufs: 16384*256 each
    const long long B_LN0    = B_ENC + 4194304;
    const long long B_XN     = B_LN0 + 4194304;
    const long long B_M1     = B_XN  + 4194304;
    const long long B_M2     = B_M1  + 4194304;
    const long long B_MASKED = B_M2  + 4194304;

    PrepArgs pa;
    for (int i = 0; i < 21; i++) { pa.src[i] = d_in[i]; pa.off[i] = O[i]; pa.n[i] = in_sizes[i]; pa.kind[i] = 0; }
    pa.src[21] = d_in[6];  pa.off[21] = WB_INIT;  pa.n[21] = 65536;  pa.kind[21] = 1;
    pa.src[22] = d_in[18]; pa.off[22] = WB_FINAL; pa.n[22] = 65536;  pa.kind[22] = 1;
    pa.src[23] = d_in[16]; pa.off[23] = WB_SKIP;  pa.n[23] = 262144; pa.kind[23] = 1;
    pa.src[24] = d_in[11]; pa.off[24] = WB_INV1;  pa.n[24] = 196608; pa.kind[24] = 1;
    pa.src[25] = d_in[2];  pa.off[25] = ACWT;     pa.n[25] = 4096;   pa.kind[25] = 2;
    pa.src[26] = d_in[3];  pa.off[26] = BCWT;     pa.n[26] = 4096;   pa.kind[26] = 2;
    pa.src[27] = d_in[20]; pa.off[27] = WB_DEC;   pa.n[27] = 4096;   pa.kind[27] = 3;
    k_prep<<<dim3(64, 28), 256, 0, stream>>>(pa, W, H, probe);

    // encoder + me-LN: enc(bf16) and LN(enc)(bf16)
    k_encoder_ln<<<dim3(512, 4), 256, 0, stream>>>(W + O[0], W + O[1], W + ACWT, W + BCWT,
                                                   W + O[4], W + O[5], H + B_ENC, H + B_LN0);

    // me_init GEMM + prelu(a0) + LN(g0,b0) -> xn_0
    k_gemm_fused<<<512, 256, 0, stream>>>(H + B_LN0, H + WB_INIT, W + O[7],
                                          nullptr, W + O[10] + 0, W + O[8], W + O[9],
                                          nullptr, 0, H + B_XN);

    for (int b = 0; b < 4; b++) {
        const long long srcs[3] = {B_XN, B_M1, B_M2};
        const long long dsts[3] = {B_M1, B_M2, B_M1};
        for (int p = 0; p < 3; p++) {
            const int bp = b * 3 + p;
            k_inv<<<512, 256, 0, stream>>>(H + srcs[p], H + WB_INV1 + (long long)bp * 16384,
                                           W + O[12] + bp * 64, W + O[13] + bp * 192,
                                           W + O[14] + bp * 3, W + O[15] + bp * 256, H + dsts[p]);
        }
        if (b < 3) {
            k_gemm_fused<<<512, 256, 0, stream>>>(H + B_XN, H + WB_SKIP + (long long)b * 65536,
                                                  W + O[17] + b * 256, H + B_M1,
                                                  W + O[10] + b + 1,
                                                  W + O[8] + (b + 1) * 256, W + O[9] + (b + 1) * 256,
                                                  nullptr, 0, H + B_XN);
        } else {
            k_gemm_fused<<<512, 256, 0, stream>>>(H + B_XN, H + WB_SKIP + (long long)b * 65536,
                                                  W + O[17] + b * 256, H + B_M1,
                                                  nullptr, nullptr, nullptr,
                                                  nullptr, 0, H + B_M2);
        }
    }

    // masked = enc * relu(me_final(x))
    k_gemm_fused<<<512, 256, 0, stream>>>(H + B_M2, H + WB_FINAL, W + O[19],
                                          nullptr, nullptr, nullptr, nullptr,
                                          H + B_ENC, 1, H + B_MASKED);

    k_deconv<<<512, 256, 0, stream>>>(H + B_MASKED, H + WB_DEC, d_out, probe);
}